// Round 5
// baseline (595.318 us; speedup 1.0000x reference)
//
#include <hip/hip_runtime.h>
#include <math.h>

#define DIM_IN  500
#define DIM_HID 128
#define DIM_OUT 40
#define NQ4     125   // DIM_IN/4 float4s per row
#define PERQ    63    // float4s per K-chunk (2 chunks); LDS = 63*160*4 = 40320 B

// ---------------- small generic matmul (weight fusion), 4-way k-unroll ----------------
__global__ void mm_small(const float* __restrict__ A, const float* __restrict__ B,
                         float* __restrict__ C, int M, int K, int Nc) {
    int idx = blockIdx.x * blockDim.x + threadIdx.x;
    if (idx >= M * Nc) return;
    int i = idx / Nc, j = idx - i * Nc;
    const float* a = A + (size_t)i * K;
    const float* b = B + j;
    float s0 = 0.f, s1 = 0.f, s2 = 0.f, s3 = 0.f;
    int k = 0;
    for (; k + 4 <= K; k += 4) {
        s0 = fmaf(a[k],     b[(size_t)k * Nc],       s0);
        s1 = fmaf(a[k + 1], b[(size_t)(k + 1) * Nc], s1);
        s2 = fmaf(a[k + 2], b[(size_t)(k + 2) * Nc], s2);
        s3 = fmaf(a[k + 3], b[(size_t)(k + 3) * Nc], s3);
    }
    for (; k < K; ++k) s0 = fmaf(a[k], b[(size_t)k * Nc], s0);
    C[idx] = (s0 + s1) + (s2 + s3);
}

// ---------------- degree histogram (in-degree over col) ----------------
__global__ void degree_k(const int* __restrict__ col, unsigned* __restrict__ deg, int E) {
    int e = blockIdx.x * blockDim.x + threadIdx.x;
    if (e < E) atomicAdd(&deg[col[e]], 1u);
}

__global__ void dinv_k(const unsigned* __restrict__ deg, float* __restrict__ dinv, int N) {
    int i = blockIdx.x * blockDim.x + threadIdx.x;
    if (i < N) dinv[i] = rsqrtf((float)deg[i] + 1.0f);   // +1 = self loop
}

// ---------------- single-block exclusive scan (4 elems/thread) ----------------
__global__ __launch_bounds__(1024) void scan_block4(const unsigned* __restrict__ deg,
                                                    unsigned* __restrict__ off,
                                                    unsigned* __restrict__ cur, int N) {
    const int t = threadIdx.x, lane = t & 63, wid = t >> 6;
    const int N4 = (N + 3) >> 2;
    __shared__ unsigned wsum[16];
    __shared__ unsigned carry_s;
    if (t == 0) carry_s = 0;
    __syncthreads();
    for (int base = 0; base < N4; base += 1024) {
        int i = base + t;
        unsigned d0 = 0, d1 = 0, d2 = 0, d3 = 0;
        if (4 * i + 3 < N) {
            uint4 d = reinterpret_cast<const uint4*>(deg)[i];
            d0 = d.x; d1 = d.y; d2 = d.z; d3 = d.w;
        } else if (4 * i < N) {
            d0 = deg[4 * i];
            if (4 * i + 1 < N) d1 = deg[4 * i + 1];
            if (4 * i + 2 < N) d2 = deg[4 * i + 2];
        }
        unsigned tsum = d0 + d1 + d2 + d3;
        unsigned v = tsum;
#pragma unroll
        for (int o = 1; o < 64; o <<= 1) {
            unsigned u = __shfl_up(v, o);
            if (lane >= o) v += u;
        }
        if (lane == 63) wsum[wid] = v;
        __syncthreads();
        if (wid == 0) {
            unsigned w = (lane < 16) ? wsum[lane] : 0u;
#pragma unroll
            for (int o = 1; o < 16; o <<= 1) {
                unsigned u = __shfl_up(w, o);
                if (lane >= o) w += u;
            }
            if (lane < 16) wsum[lane] = w;
        }
        __syncthreads();
        unsigned excl = carry_s + (wid ? wsum[wid - 1] : 0u) + (v - tsum);
        unsigned o0 = excl, o1 = o0 + d0, o2 = o1 + d1, o3 = o2 + d2;
        if (4 * i + 3 < N) {
            reinterpret_cast<uint4*>(off)[i] = make_uint4(o0, o1, o2, o3);
            reinterpret_cast<uint4*>(cur)[i] = make_uint4(o0, o1, o2, o3);
        } else if (4 * i < N) {
            off[4 * i] = o0; cur[4 * i] = o0;
            if (4 * i + 1 < N) { off[4 * i + 1] = o1; cur[4 * i + 1] = o1; }
            if (4 * i + 2 < N) { off[4 * i + 2] = o2; cur[4 * i + 2] = o2; }
        }
        __syncthreads();
        if (t == 0) carry_s += wsum[15];
        __syncthreads();
    }
    if (t == 0) off[N] = carry_s;
}

// ---------------- scatter edges into CSR (by col); stores source rows ----------------
__global__ void scatter_k(const int* __restrict__ row, const int* __restrict__ col,
                          unsigned* __restrict__ cur, int* __restrict__ srow, int E) {
    int e = blockIdx.x * blockDim.x + threadIdx.x;
    if (e < E) {
        unsigned p = atomicAdd(&cur[col[e]], 1u);
        srow[p] = row[e];
    }
}

// ---------------- GEMM: G += dinv[r] * (X[r, chunk] @ Wf[chunk, :]) via fp32 atomics ----
// 2 chunks (blockIdx.y), W-chunk in LDS, 1 row/thread, sequential float4 X reads.
// Determinism: G starts at 0.0; two commutative fp32 adds -> order-independent result.
__global__ __launch_bounds__(256) void gemm_atomic(const float* __restrict__ X,
                                                   const float* __restrict__ Wf,
                                                   const float* __restrict__ dinv,
                                                   float* __restrict__ G, int N) {
    __shared__ float Ws[PERQ * 4 * DIM_OUT];        // 40320 B -> 4 blocks/CU
    const int tid = threadIdx.x;
    const int ch  = blockIdx.y;
    const int q0  = ch * PERQ;
    const int cnt = min(NQ4 - q0, PERQ);            // 63 / 62

    {   // stage W chunk, coalesced float4
        const float4* wsrc = reinterpret_cast<const float4*>(Wf + (size_t)q0 * 4 * DIM_OUT);
        const int nv = cnt * DIM_OUT;
        for (int i = tid; i < nv; i += 256) reinterpret_cast<float4*>(Ws)[i] = wsrc[i];
    }
    __syncthreads();

    const int r = blockIdx.x * 256 + tid;
    if (r >= N) return;
    const float4* xr = reinterpret_cast<const float4*>(X + (size_t)r * DIM_IN) + q0;

    float acc[DIM_OUT];
#pragma unroll
    for (int j = 0; j < DIM_OUT; ++j) acc[j] = 0.f;

    float4 a0 = xr[0];
    float4 a1 = xr[1];
    for (int q = 0; q < cnt; ++q) {
        float4 nx = xr[(q + 2 < cnt) ? q + 2 : q];  // 2-deep prefetch
        const float* w = Ws + q * 4 * DIM_OUT;
#pragma unroll
        for (int kk = 0; kk < 4; ++kk) {
            const float av = (kk == 0) ? a0.x : (kk == 1) ? a0.y : (kk == 2) ? a0.z : a0.w;
            const float* wk = w + kk * DIM_OUT;
#pragma unroll
            for (int j4 = 0; j4 < DIM_OUT / 4; ++j4) {
                float4 wv = *reinterpret_cast<const float4*>(wk + j4 * 4);   // LDS broadcast
                acc[4 * j4]     = fmaf(av, wv.x, acc[4 * j4]);
                acc[4 * j4 + 1] = fmaf(av, wv.y, acc[4 * j4 + 1]);
                acc[4 * j4 + 2] = fmaf(av, wv.z, acc[4 * j4 + 2]);
                acc[4 * j4 + 3] = fmaf(av, wv.w, acc[4 * j4 + 3]);
            }
        }
        a0 = a1; a1 = nx;
    }

    const float d = dinv[r];
    float* gr = G + (size_t)r * DIM_OUT;
#pragma unroll
    for (int j = 0; j < DIM_OUT; ++j) atomicAdd(&gr[j], acc[j] * d);
}

// ---------------- aggregation: 5 threads/node, 2 adjacent quads each ----------------
// SCALED=1: out = d*(d*acc + bias)   (feeds next layer, pre-scaled by dinv)
// SCALED=0: out = d*acc              (last layer; b3 folded into logsoftmax)
template <int SCALED>
__global__ __launch_bounds__(256) void agg8(const unsigned* __restrict__ off,
                                            const int* __restrict__ srow,
                                            const float* __restrict__ dinv,
                                            const float4* __restrict__ G4,
                                            const float4* __restrict__ bias4,
                                            float4* __restrict__ out4, int N) {
    const int idx = blockIdx.x * blockDim.x + threadIdx.x;
    if (idx >= N * 5) return;
    const int c = idx / 5;
    const int v = (idx - c * 5) * 2;                 // 0,2,4,6,8
    const unsigned beg = off[c], end = off[c + 1];
    const size_t base = (size_t)c * (DIM_OUT / 4);

    float4 pa = G4[base + v], pb = G4[base + v + 1];     // self loop
    float4 qa = make_float4(0, 0, 0, 0), qb = make_float4(0, 0, 0, 0);
    float4 ra = make_float4(0, 0, 0, 0), rb = make_float4(0, 0, 0, 0);
    float4 sa = make_float4(0, 0, 0, 0), sb = make_float4(0, 0, 0, 0);

    unsigned e = beg;
    for (; e + 4 <= end; e += 4) {                   // 8 gathers in flight per lane
        int r0 = srow[e], r1 = srow[e + 1], r2 = srow[e + 2], r3 = srow[e + 3];
        const float4* g0 = G4 + (size_t)r0 * (DIM_OUT / 4) + v;
        const float4* g1 = G4 + (size_t)r1 * (DIM_OUT / 4) + v;
        const float4* g2 = G4 + (size_t)r2 * (DIM_OUT / 4) + v;
        const float4* g3 = G4 + (size_t)r3 * (DIM_OUT / 4) + v;
        float4 u0 = g0[0], w0 = g0[1];
        float4 u1 = g1[0], w1 = g1[1];
        float4 u2 = g2[0], w2 = g2[1];
        float4 u3 = g3[0], w3 = g3[1];
        pa.x += u0.x; pa.y += u0.y; pa.z += u0.z; pa.w += u0.w;
        pb.x += w0.x; pb.y += w0.y; pb.z += w0.z; pb.w += w0.w;
        qa.x += u1.x; qa.y += u1.y; qa.z += u1.z; qa.w += u1.w;
        qb.x += w1.x; qb.y += w1.y; qb.z += w1.z; qb.w += w1.w;
        ra.x += u2.x; ra.y += u2.y; ra.z += u2.z; ra.w += u2.w;
        rb.x += w2.x; rb.y += w2.y; rb.z += w2.z; rb.w += w2.w;
        sa.x += u3.x; sa.y += u3.y; sa.z += u3.z; sa.w += u3.w;
        sb.x += w3.x; sb.y += w3.y; sb.z += w3.z; sb.w += w3.w;
    }
    for (; e < end; ++e) {
        const float4* g = G4 + (size_t)srow[e] * (DIM_OUT / 4) + v;
        float4 u = g[0], w = g[1];
        pa.x += u.x; pa.y += u.y; pa.z += u.z; pa.w += u.w;
        pb.x += w.x; pb.y += w.y; pb.z += w.z; pb.w += w.w;
    }
    float4 A = make_float4((pa.x + qa.x) + (ra.x + sa.x), (pa.y + qa.y) + (ra.y + sa.y),
                           (pa.z + qa.z) + (ra.z + sa.z), (pa.w + qa.w) + (ra.w + sa.w));
    float4 B = make_float4((pb.x + qb.x) + (rb.x + sb.x), (pb.y + qb.y) + (rb.y + sb.y),
                           (pb.z + qb.z) + (rb.z + sb.z), (pb.w + qb.w) + (rb.w + sb.w));
    const float d = dinv[c];
    float4 oA, oB;
    if (SCALED) {
        float4 b0 = bias4[v], b1 = bias4[v + 1];
        oA = make_float4(d * (d * A.x + b0.x), d * (d * A.y + b0.y),
                         d * (d * A.z + b0.z), d * (d * A.w + b0.w));
        oB = make_float4(d * (d * B.x + b1.x), d * (d * B.y + b1.y),
                         d * (d * B.z + b1.z), d * (d * B.w + b1.w));
    } else {
        oA = make_float4(d * A.x, d * A.y, d * A.z, d * A.w);
        oB = make_float4(d * B.x, d * B.y, d * B.z, d * B.w);
    }
    out4[base + v]     = oA;
    out4[base + v + 1] = oB;
}

// ---------------- log_softmax over 40 (wave per row) + final bias b3 ----------------
__global__ void logsoftmax40(const float* __restrict__ Hin, const float* __restrict__ b3,
                             float* __restrict__ out, int N) {
    int wave = (blockIdx.x * blockDim.x + threadIdx.x) >> 6;
    int lane = threadIdx.x & 63;
    if (wave >= N) return;
    float x = 0.f, v = -INFINITY;
    if (lane < DIM_OUT) {
        x = Hin[(size_t)wave * DIM_OUT + lane] + b3[lane];
        v = x;
    }
#pragma unroll
    for (int o = 32; o; o >>= 1) v = fmaxf(v, __shfl_xor(v, o));
    float ex = (lane < DIM_OUT) ? expf(x - v) : 0.f;
    float s = ex;
#pragma unroll
    for (int o = 32; o; o >>= 1) s += __shfl_xor(s, o);
    if (lane < DIM_OUT) out[(size_t)wave * DIM_OUT + lane] = x - v - logf(s);
}

// ---------------- launch ----------------
extern "C" void kernel_launch(void* const* d_in, const int* in_sizes, int n_in,
                              void* d_out, int out_size, void* d_ws, size_t ws_size,
                              hipStream_t stream) {
    const float* x  = (const float*)d_in[0];
    const int*   ei = (const int*)d_in[1];
    const float* W1 = (const float*)d_in[2];
    const float* b1 = (const float*)d_in[3];
    const float* W2 = (const float*)d_in[4];
    const float* b2 = (const float*)d_in[5];
    const float* W3 = (const float*)d_in[6];
    const float* b3 = (const float*)d_in[7];
    float* out = (float*)d_out;

    const int N = in_sizes[0] / DIM_IN;
    const int E = in_sizes[1] / 2;
    const int* row = ei;       // edge_index[0]
    const int* col = ei + E;   // edge_index[1]

    char* wsp = (char*)d_ws;
    size_t used = 0;
    auto alloc = [&](size_t bytes) -> void* {
        void* p = wsp + used;
        used += (bytes + 255) & ~(size_t)255;
        return p;
    };
    unsigned* deg  = (unsigned*)alloc((size_t)N * 4);
    unsigned* off  = (unsigned*)alloc((size_t)(N + 1) * 4);
    unsigned* cur  = (unsigned*)alloc((size_t)N * 4);
    int*      srow = (int*)alloc((size_t)E * 4);
    float*    dinv = (float*)alloc((size_t)N * 4);
    float*    W12  = (float*)alloc((size_t)DIM_IN * DIM_HID * 4);
    float*    Wf   = (float*)alloc((size_t)DIM_IN * DIM_OUT * 4);
    float*    t1   = (float*)alloc((size_t)DIM_HID * 4);
    float*    bp1  = (float*)alloc((size_t)DIM_OUT * 4);
    float*    bp2  = (float*)alloc((size_t)DIM_OUT * 4);
    float*    G0   = (float*)alloc((size_t)N * DIM_OUT * 4 + 256);
    float*    G1   = (float*)alloc((size_t)N * DIM_OUT * 4 + 256);

    // ---- CSR build + normalization ----
    hipMemsetAsync(deg, 0, (size_t)N * 4, stream);
    degree_k<<<(E + 255) / 256, 256, 0, stream>>>(col, deg, E);
    scan_block4<<<1, 1024, 0, stream>>>(deg, off, cur, N);
    dinv_k<<<(N + 255) / 256, 256, 0, stream>>>(deg, dinv, N);
    scatter_k<<<(E + 255) / 256, 256, 0, stream>>>(row, col, cur, srow, E);

    // ---- weight fusion: Wf = W1@W2@W3; bp1 = b1@W2@W3; bp2 = b2@W3 ----
    mm_small<<<(DIM_IN * DIM_HID + 255) / 256, 256, 0, stream>>>(W1, W2, W12, DIM_IN, DIM_HID, DIM_HID);
    mm_small<<<(DIM_IN * DIM_OUT + 255) / 256, 256, 0, stream>>>(W12, W3, Wf, DIM_IN, DIM_HID, DIM_OUT);
    mm_small<<<1, 256, 0, stream>>>(b1, W2, t1, 1, DIM_HID, DIM_HID);
    mm_small<<<1, 64, 0, stream>>>(t1, W3, bp1, 1, DIM_HID, DIM_OUT);
    mm_small<<<1, 64, 0, stream>>>(b2, W3, bp2, 1, DIM_HID, DIM_OUT);

    // ---- G0 = dinv .* (X @ Wf), atomic accumulation over 2 K-chunks ----
    hipMemsetAsync(G0, 0, (size_t)N * DIM_OUT * 4, stream);
    {
        dim3 grid((N + 255) / 256, 2);
        gemm_atomic<<<grid, 256, 0, stream>>>(x, Wf, dinv, G0, N);
    }

    // ---- three aggregations (5 threads per node, 2 quads each) ----
    const int aggGrid = (N * 5 + 255) / 256;
    agg8<1><<<aggGrid, 256, 0, stream>>>(off, srow, dinv, (const float4*)G0, (const float4*)bp1, (float4*)G1, N);
    agg8<1><<<aggGrid, 256, 0, stream>>>(off, srow, dinv, (const float4*)G1, (const float4*)bp2, (float4*)G0, N);
    agg8<0><<<aggGrid, 256, 0, stream>>>(off, srow, dinv, (const float4*)G0, nullptr, (float4*)G1, N);

    // ---- out = log_softmax(G1 + b3) ----
    logsoftmax40<<<(N + 3) / 4, 256, 0, stream>>>(G1, b3, out, N);
}

// Round 6
// 406.496 us; speedup vs baseline: 1.4645x; 1.4645x over previous
//
#include <hip/hip_runtime.h>
#include <math.h>

#define DIM_IN  500
#define DIM_HID 128
#define DIM_OUT 40
#define NQ4     125   // DIM_IN/4 float4s per row
#define NCH     4     // K-chunks for main GEMM
#define PERQ    32    // float4s per chunk (last chunk: 29, zero-padded W)

// ---------------- small generic matmul (weight fusion, tiny) ----------------
__global__ void mm_small(const float* __restrict__ A, const float* __restrict__ B,
                         float* __restrict__ C, int M, int K, int Nc) {
    int idx = blockIdx.x * blockDim.x + threadIdx.x;
    if (idx >= M * Nc) return;
    int i = idx / Nc, j = idx - i * Nc;
    const float* a = A + (size_t)i * K;
    const float* b = B + j;
    float s0 = 0.f, s1 = 0.f, s2 = 0.f, s3 = 0.f;
    int k = 0;
    for (; k + 4 <= K; k += 4) {
        s0 = fmaf(a[k],     b[(size_t)k * Nc],       s0);
        s1 = fmaf(a[k + 1], b[(size_t)(k + 1) * Nc], s1);
        s2 = fmaf(a[k + 2], b[(size_t)(k + 2) * Nc], s2);
        s3 = fmaf(a[k + 3], b[(size_t)(k + 3) * Nc], s3);
    }
    for (; k < K; ++k) s0 = fmaf(a[k], b[(size_t)k * Nc], s0);
    C[idx] = (s0 + s1) + (s2 + s3);
}

// ---------------- both fused biases in one launch ----------------
// bp1 = b1 @ W23 (K=128), bp2 = b2 @ W3 (K=128)
__global__ void bias_fuse(const float* __restrict__ b1, const float* __restrict__ W23,
                          const float* __restrict__ b2, const float* __restrict__ W3,
                          float* __restrict__ bp1, float* __restrict__ bp2) {
    int t = threadIdx.x;
    if (t < DIM_OUT) {
        float s = 0.f;
        for (int k = 0; k < DIM_HID; ++k) s = fmaf(b1[k], W23[k * DIM_OUT + t], s);
        bp1[t] = s;
    } else if (t < 2 * DIM_OUT) {
        int j = t - DIM_OUT;
        float s = 0.f;
        for (int k = 0; k < DIM_HID; ++k) s = fmaf(b2[k], W3[k * DIM_OUT + j], s);
        bp2[j] = s;
    }
}

// ---------------- degree histogram (in-degree over col) ----------------
__global__ void degree_k(const int* __restrict__ col, unsigned* __restrict__ deg, int E) {
    int e = blockIdx.x * blockDim.x + threadIdx.x;
    if (e < E) atomicAdd(&deg[col[e]], 1u);
}

// ---------------- single-block exclusive scan (4 elems/thread) + dinv ----------------
__global__ __launch_bounds__(1024) void scan_block4(const unsigned* __restrict__ deg,
                                                    unsigned* __restrict__ off,
                                                    unsigned* __restrict__ cur,
                                                    float* __restrict__ dinv, int N) {
    const int t = threadIdx.x, lane = t & 63, wid = t >> 6;
    const int N4 = (N + 3) >> 2;
    __shared__ unsigned wsum[16];
    __shared__ unsigned carry_s;
    if (t == 0) carry_s = 0;
    __syncthreads();
    for (int base = 0; base < N4; base += 1024) {
        int i = base + t;
        unsigned d0 = 0, d1 = 0, d2 = 0, d3 = 0;
        if (4 * i + 3 < N) {
            uint4 d = reinterpret_cast<const uint4*>(deg)[i];
            d0 = d.x; d1 = d.y; d2 = d.z; d3 = d.w;
        } else if (4 * i < N) {
            d0 = deg[4 * i];
            if (4 * i + 1 < N) d1 = deg[4 * i + 1];
            if (4 * i + 2 < N) d2 = deg[4 * i + 2];
        }
        unsigned tsum = d0 + d1 + d2 + d3;
        unsigned v = tsum;
#pragma unroll
        for (int o = 1; o < 64; o <<= 1) {
            unsigned u = __shfl_up(v, o);
            if (lane >= o) v += u;
        }
        if (lane == 63) wsum[wid] = v;
        __syncthreads();
        if (wid == 0) {
            unsigned w = (lane < 16) ? wsum[lane] : 0u;
#pragma unroll
            for (int o = 1; o < 16; o <<= 1) {
                unsigned u = __shfl_up(w, o);
                if (lane >= o) w += u;
            }
            if (lane < 16) wsum[lane] = w;
        }
        __syncthreads();
        unsigned excl = carry_s + (wid ? wsum[wid - 1] : 0u) + (v - tsum);
        unsigned o0 = excl, o1 = o0 + d0, o2 = o1 + d1, o3 = o2 + d2;
        if (4 * i + 3 < N) {
            reinterpret_cast<uint4*>(off)[i] = make_uint4(o0, o1, o2, o3);
            reinterpret_cast<uint4*>(cur)[i] = make_uint4(o0, o1, o2, o3);
            reinterpret_cast<float4*>(dinv)[i] =
                make_float4(rsqrtf((float)d0 + 1.f), rsqrtf((float)d1 + 1.f),
                            rsqrtf((float)d2 + 1.f), rsqrtf((float)d3 + 1.f));
        } else if (4 * i < N) {
            off[4 * i] = o0; cur[4 * i] = o0; dinv[4 * i] = rsqrtf((float)d0 + 1.f);
            if (4 * i + 1 < N) { off[4 * i + 1] = o1; cur[4 * i + 1] = o1; dinv[4 * i + 1] = rsqrtf((float)d1 + 1.f); }
            if (4 * i + 2 < N) { off[4 * i + 2] = o2; cur[4 * i + 2] = o2; dinv[4 * i + 2] = rsqrtf((float)d2 + 1.f); }
        }
        __syncthreads();
        if (t == 0) carry_s += wsum[15];
        __syncthreads();
    }
    if (t == 0) off[N] = carry_s;
}

// ---------------- scatter edges into CSR (by col); stores source rows ----------------
__global__ void scatter_k(const int* __restrict__ row, const int* __restrict__ col,
                          unsigned* __restrict__ cur, int* __restrict__ srow, int E) {
    int e = blockIdx.x * blockDim.x + threadIdx.x;
    if (e < E) {
        unsigned p = atomicAdd(&cur[col[e]], 1u);
        srow[p] = row[e];
    }
}

// ---------------- GEMM partial: P[ch][r][:] = X[r, chunk] @ Wf[chunk, :] ----------------
// W-chunk in LDS (broadcast ds_read_b128), 1 row/thread, 64B-per-macro-iter X reads.
__global__ __launch_bounds__(256) void gemm_v6(const float* __restrict__ X,
                                               const float* __restrict__ Wf,
                                               float* __restrict__ P, int N) {
    __shared__ float Ws[PERQ * 4 * DIM_OUT];        // 20480 B -> 8 blocks/CU by LDS
    const int tid = threadIdx.x;
    const int ch  = blockIdx.y;
    const int q0  = ch * PERQ;
    const int cnt = min(NQ4 - q0, PERQ);            // 32,32,32,29

    {   // stage W chunk, zero-padded to PERQ
        const float4* wsrc = reinterpret_cast<const float4*>(Wf + (size_t)q0 * 4 * DIM_OUT);
        for (int i = tid; i < PERQ * DIM_OUT; i += 256)
            reinterpret_cast<float4*>(Ws)[i] =
                (i < cnt * DIM_OUT) ? wsrc[i] : make_float4(0.f, 0.f, 0.f, 0.f);
    }
    __syncthreads();

    const int r = blockIdx.x * 256 + tid;
    if (r >= N) return;
    const float4* xr = reinterpret_cast<const float4*>(X + (size_t)r * DIM_IN) + q0;
    auto ldx = [&](int q) { return xr[(q < cnt) ? q : 0]; };   // clamped; zero-W kills tail

    float acc[DIM_OUT];
#pragma unroll
    for (int j = 0; j < DIM_OUT; ++j) acc[j] = 0.f;

    float4 c0 = ldx(0), c1 = ldx(1), c2 = ldx(2), c3 = ldx(3);
    for (int m = 0; m < PERQ; m += 4) {             // 8 macro-iters; 64B X per iter
        float4 n0 = ldx(m + 4), n1 = ldx(m + 5), n2 = ldx(m + 6), n3 = ldx(m + 7);
#pragma unroll
        for (int qq = 0; qq < 4; ++qq) {
            const float4 xv = (qq == 0) ? c0 : (qq == 1) ? c1 : (qq == 2) ? c2 : c3;
            const float* w = Ws + (m + qq) * 4 * DIM_OUT;
#pragma unroll
            for (int kk = 0; kk < 4; ++kk) {
                const float av = (kk == 0) ? xv.x : (kk == 1) ? xv.y : (kk == 2) ? xv.z : xv.w;
                const float* wk = w + kk * DIM_OUT;
#pragma unroll
                for (int j4 = 0; j4 < DIM_OUT / 4; ++j4) {
                    float4 wv = *reinterpret_cast<const float4*>(wk + j4 * 4);  // LDS broadcast
                    acc[4 * j4]     = fmaf(av, wv.x, acc[4 * j4]);
                    acc[4 * j4 + 1] = fmaf(av, wv.y, acc[4 * j4 + 1]);
                    acc[4 * j4 + 2] = fmaf(av, wv.z, acc[4 * j4 + 2]);
                    acc[4 * j4 + 3] = fmaf(av, wv.w, acc[4 * j4 + 3]);
                }
            }
        }
        c0 = n0; c1 = n1; c2 = n2; c3 = n3;
    }

    float4* pr = reinterpret_cast<float4*>(P + (size_t)ch * N * DIM_OUT + (size_t)r * DIM_OUT);
#pragma unroll
    for (int v = 0; v < DIM_OUT / 4; ++v)
        pr[v] = make_float4(acc[4 * v], acc[4 * v + 1], acc[4 * v + 2], acc[4 * v + 3]);
}

// ---------------- reduce partials + scale: G[r][j] = dinv[r] * sum_ch P[ch][r][j] ----------------
__global__ __launch_bounds__(256) void reduce_scale(const float* __restrict__ P,
                                                    const float* __restrict__ dinv,
                                                    float* __restrict__ G, int N) {
    int idx = blockIdx.x * blockDim.x + threadIdx.x;      // over N*10 float4s
    if (idx >= N * (DIM_OUT / 4)) return;
    int r = idx / (DIM_OUT / 4);
    const size_t plane = (size_t)N * (DIM_OUT / 4);
    const float4* p = reinterpret_cast<const float4*>(P) + idx;
    float4 s = p[0];
#pragma unroll
    for (int c = 1; c < NCH; ++c) {
        float4 v = p[c * plane];
        s.x += v.x; s.y += v.y; s.z += v.z; s.w += v.w;
    }
    float d = dinv[r];
    s.x *= d; s.y *= d; s.z *= d; s.w *= d;
    reinterpret_cast<float4*>(G)[idx] = s;
}

// ---------------- aggregation: 5 threads/node, 2 adjacent quads each ----------------
// SCALED=1: out = d*(d*acc + bias)   SCALED=0: out = d*acc (b3 folded into logsoftmax)
template <int SCALED>
__global__ __launch_bounds__(256) void agg8(const unsigned* __restrict__ off,
                                            const int* __restrict__ srow,
                                            const float* __restrict__ dinv,
                                            const float4* __restrict__ G4,
                                            const float4* __restrict__ bias4,
                                            float4* __restrict__ out4, int N) {
    const int idx = blockIdx.x * blockDim.x + threadIdx.x;
    if (idx >= N * 5) return;
    const int c = idx / 5;
    const int v = (idx - c * 5) * 2;                 // 0,2,4,6,8
    const unsigned beg = off[c], end = off[c + 1];
    const size_t base = (size_t)c * (DIM_OUT / 4);

    float4 pa = G4[base + v], pb = G4[base + v + 1];     // self loop
    float4 qa = make_float4(0, 0, 0, 0), qb = make_float4(0, 0, 0, 0);
    float4 ra = make_float4(0, 0, 0, 0), rb = make_float4(0, 0, 0, 0);
    float4 sa = make_float4(0, 0, 0, 0), sb = make_float4(0, 0, 0, 0);

    unsigned e = beg;
    for (; e + 4 <= end; e += 4) {                   // 8 gathers in flight per lane
        int r0 = srow[e], r1 = srow[e + 1], r2 = srow[e + 2], r3 = srow[e + 3];
        const float4* g0 = G4 + (size_t)r0 * (DIM_OUT / 4) + v;
        const float4* g1 = G4 + (size_t)r1 * (DIM_OUT / 4) + v;
        const float4* g2 = G4 + (size_t)r2 * (DIM_OUT / 4) + v;
        const float4* g3 = G4 + (size_t)r3 * (DIM_OUT / 4) + v;
        float4 u0 = g0[0], w0 = g0[1];
        float4 u1 = g1[0], w1 = g1[1];
        float4 u2 = g2[0], w2 = g2[1];
        float4 u3 = g3[0], w3 = g3[1];
        pa.x += u0.x; pa.y += u0.y; pa.z += u0.z; pa.w += u0.w;
        pb.x += w0.x; pb.y += w0.y; pb.z += w0.z; pb.w += w0.w;
        qa.x += u1.x; qa.y += u1.y; qa.z += u1.z; qa.w += u1.w;
        qb.x += w1.x; qb.y += w1.y; qb.z += w1.z; qb.w += w1.w;
        ra.x += u2.x; ra.y += u2.y; ra.z += u2.z; ra.w += u2.w;
        rb.x += w2.x; rb.y += w2.y; rb.z += w2.z; rb.w += w2.w;
        sa.x += u3.x; sa.y += u3.y; sa.z += u3.z; sa.w += u3.w;
        sb.x += w3.x; sb.y += w3.y; sb.z += w3.z; sb.w += w3.w;
    }
    for (; e < end; ++e) {
        const float4* g = G4 + (size_t)srow[e] * (DIM_OUT / 4) + v;
        float4 u = g[0], w = g[1];
        pa.x += u.x; pa.y += u.y; pa.z += u.z; pa.w += u.w;
        pb.x += w.x; pb.y += w.y; pb.z += w.z; pb.w += w.w;
    }
    float4 A = make_float4((pa.x + qa.x) + (ra.x + sa.x), (pa.y + qa.y) + (ra.y + sa.y),
                           (pa.z + qa.z) + (ra.z + sa.z), (pa.w + qa.w) + (ra.w + sa.w));
    float4 B = make_float4((pb.x + qb.x) + (rb.x + sb.x), (pb.y + qb.y) + (rb.y + sb.y),
                           (pb.z + qb.z) + (rb.z + sb.z), (pb.w + qb.w) + (rb.w + sb.w));
    const float d = dinv[c];
    float4 oA, oB;
    if (SCALED) {
        float4 b0 = bias4[v], b1 = bias4[v + 1];
        oA = make_float4(d * (d * A.x + b0.x), d * (d * A.y + b0.y),
                         d * (d * A.z + b0.z), d * (d * A.w + b0.w));
        oB = make_float4(d * (d * B.x + b1.x), d * (d * B.y + b1.y),
                         d * (d * B.z + b1.z), d * (d * B.w + b1.w));
    } else {
        oA = make_float4(d * A.x, d * A.y, d * A.z, d * A.w);
        oB = make_float4(d * B.x, d * B.y, d * B.z, d * B.w);
    }
    out4[base + v]     = oA;
    out4[base + v + 1] = oB;
}

// ---------------- log_softmax over 40 (wave per row) + final bias b3 ----------------
__global__ void logsoftmax40(const float* __restrict__ Hin, const float* __restrict__ b3,
                             float* __restrict__ out, int N) {
    int wave = (blockIdx.x * blockDim.x + threadIdx.x) >> 6;
    int lane = threadIdx.x & 63;
    if (wave >= N) return;
    float x = 0.f, v = -INFINITY;
    if (lane < DIM_OUT) {
        x = Hin[(size_t)wave * DIM_OUT + lane] + b3[lane];
        v = x;
    }
#pragma unroll
    for (int o = 32; o; o >>= 1) v = fmaxf(v, __shfl_xor(v, o));
    float ex = (lane < DIM_OUT) ? expf(x - v) : 0.f;
    float s = ex;
#pragma unroll
    for (int o = 32; o; o >>= 1) s += __shfl_xor(s, o);
    if (lane < DIM_OUT) out[(size_t)wave * DIM_OUT + lane] = x - v - logf(s);
}

// ---------------- launch ----------------
extern "C" void kernel_launch(void* const* d_in, const int* in_sizes, int n_in,
                              void* d_out, int out_size, void* d_ws, size_t ws_size,
                              hipStream_t stream) {
    const float* x  = (const float*)d_in[0];
    const int*   ei = (const int*)d_in[1];
    const float* W1 = (const float*)d_in[2];
    const float* b1 = (const float*)d_in[3];
    const float* W2 = (const float*)d_in[4];
    const float* b2 = (const float*)d_in[5];
    const float* W3 = (const float*)d_in[6];
    const float* b3 = (const float*)d_in[7];
    float* out = (float*)d_out;

    const int N = in_sizes[0] / DIM_IN;
    const int E = in_sizes[1] / 2;
    const int* row = ei;       // edge_index[0]
    const int* col = ei + E;   // edge_index[1]

    char* wsp = (char*)d_ws;
    size_t used = 0;
    auto alloc = [&](size_t bytes) -> void* {
        void* p = wsp + used;
        used += (bytes + 255) & ~(size_t)255;
        return p;
    };
    unsigned* deg  = (unsigned*)alloc((size_t)N * 4);
    unsigned* off  = (unsigned*)alloc((size_t)(N + 1) * 4);
    unsigned* cur  = (unsigned*)alloc((size_t)N * 4);
    int*      srow = (int*)alloc((size_t)E * 4);
    float*    dinv = (float*)alloc((size_t)N * 4);
    float*    W23  = (float*)alloc((size_t)DIM_HID * DIM_OUT * 4);
    float*    Wf   = (float*)alloc((size_t)DIM_IN * DIM_OUT * 4);
    float*    bp1  = (float*)alloc((size_t)DIM_OUT * 4);
    float*    bp2  = (float*)alloc((size_t)DIM_OUT * 4);
    float*    G0   = (float*)alloc((size_t)N * DIM_OUT * 4 + 256);
    float*    G1   = (float*)alloc((size_t)N * DIM_OUT * 4 + 256);
    float*    P    = (float*)alloc((size_t)NCH * N * DIM_OUT * 4 + 256);

    // ---- CSR build + normalization ----
    hipMemsetAsync(deg, 0, (size_t)N * 4, stream);
    degree_k<<<(E + 255) / 256, 256, 0, stream>>>(col, deg, E);
    scan_block4<<<1, 1024, 0, stream>>>(deg, off, cur, dinv, N);
    scatter_k<<<(E + 255) / 256, 256, 0, stream>>>(row, col, cur, srow, E);

    // ---- weight fusion (small-first association): W23 = W2@W3; Wf = W1@W23 ----
    mm_small<<<(DIM_HID * DIM_OUT + 255) / 256, 256, 0, stream>>>(W2, W3, W23, DIM_HID, DIM_HID, DIM_OUT);
    mm_small<<<(DIM_IN * DIM_OUT + 255) / 256, 256, 0, stream>>>(W1, W23, Wf, DIM_IN, DIM_HID, DIM_OUT);
    bias_fuse<<<1, 2 * DIM_OUT + 48, 0, stream>>>(b1, W23, b2, W3, bp1, bp2);

    // ---- G0 = dinv .* (X @ Wf) via 4 K-chunk partials + reduce ----
    {
        dim3 grid((N + 255) / 256, NCH);
        gemm_v6<<<grid, 256, 0, stream>>>(x, Wf, P, N);
        reduce_scale<<<(N * (DIM_OUT / 4) + 255) / 256, 256, 0, stream>>>(P, dinv, G0, N);
    }

    // ---- three aggregations (5 threads per node, 2 quads each) ----
    const int aggGrid = (N * 5 + 255) / 256;
    agg8<1><<<aggGrid, 256, 0, stream>>>(off, srow, dinv, (const float4*)G0, (const float4*)bp1, (float4*)G1, N);
    agg8<1><<<aggGrid, 256, 0, stream>>>(off, srow, dinv, (const float4*)G1, (const float4*)bp2, (float4*)G0, N);
    agg8<0><<<aggGrid, 256, 0, stream>>>(off, srow, dinv, (const float4*)G0, nullptr, (float4*)G1, N);

    // ---- out = log_softmax(G1 + b3) ----
    logsoftmax40<<<(N + 3) / 4, 256, 0, stream>>>(G1, b3, out, N);
}

// Round 7
// 382.307 us; speedup vs baseline: 1.5572x; 1.0633x over previous
//
#include <hip/hip_runtime.h>
#include <math.h>

#define DIM_IN  500
#define DIM_HID 128
#define DIM_OUT 40
#define NQ4     125   // DIM_IN/4 float4s per row
#define NCH     4     // K-chunks for main GEMM
#define PERQ    32    // float4s per chunk (last chunk: 29, zero-padded W)
#define ROWU4   5     // uint4s per packed bf16 row (40 dims)

// ---- bf16 pack/unpack helpers (bf16 = high 16 bits of fp32, RNE rounding) ----
__device__ __forceinline__ unsigned bf_pair(float a, float b) {
    unsigned ua = __float_as_uint(a);
    unsigned ub = __float_as_uint(b);
    ua = (ua + 0x7FFFu + ((ua >> 16) & 1u)) >> 16;          // low 16
    ub = (ub + 0x7FFFu + ((ub >> 16) & 1u)) & 0xFFFF0000u;  // high 16
    return ua | ub;
}
__device__ __forceinline__ void bf_unpack(unsigned u, float& lo, float& hi) {
    lo = __uint_as_float(u << 16);
    hi = __uint_as_float(u & 0xFFFF0000u);
}

// ---------------- small generic matmul (weight fusion, tiny) ----------------
__global__ void mm_small(const float* __restrict__ A, const float* __restrict__ B,
                         float* __restrict__ C, int M, int K, int Nc) {
    int idx = blockIdx.x * blockDim.x + threadIdx.x;
    if (idx >= M * Nc) return;
    int i = idx / Nc, j = idx - i * Nc;
    const float* a = A + (size_t)i * K;
    const float* b = B + j;
    float s0 = 0.f, s1 = 0.f, s2 = 0.f, s3 = 0.f;
    int k = 0;
    for (; k + 4 <= K; k += 4) {
        s0 = fmaf(a[k],     b[(size_t)k * Nc],       s0);
        s1 = fmaf(a[k + 1], b[(size_t)(k + 1) * Nc], s1);
        s2 = fmaf(a[k + 2], b[(size_t)(k + 2) * Nc], s2);
        s3 = fmaf(a[k + 3], b[(size_t)(k + 3) * Nc], s3);
    }
    for (; k < K; ++k) s0 = fmaf(a[k], b[(size_t)k * Nc], s0);
    C[idx] = (s0 + s1) + (s2 + s3);
}

// bp1 = b1 @ W23 (K=128), bp2 = b2 @ W3 (K=128)
__global__ void bias_fuse(const float* __restrict__ b1, const float* __restrict__ W23,
                          const float* __restrict__ b2, const float* __restrict__ W3,
                          float* __restrict__ bp1, float* __restrict__ bp2) {
    int t = threadIdx.x;
    if (t < DIM_OUT) {
        float s = 0.f;
        for (int k = 0; k < DIM_HID; ++k) s = fmaf(b1[k], W23[k * DIM_OUT + t], s);
        bp1[t] = s;
    } else if (t < 2 * DIM_OUT) {
        int j = t - DIM_OUT;
        float s = 0.f;
        for (int k = 0; k < DIM_HID; ++k) s = fmaf(b2[k], W3[k * DIM_OUT + j], s);
        bp2[j] = s;
    }
}

// ---------------- degree histogram (in-degree over col) ----------------
__global__ void degree_k(const int* __restrict__ col, unsigned* __restrict__ deg, int E) {
    int e = blockIdx.x * blockDim.x + threadIdx.x;
    if (e < E) atomicAdd(&deg[col[e]], 1u);
}

// ---------------- single-block exclusive scan (4 elems/thread) + dinv ----------------
__global__ __launch_bounds__(1024) void scan_block4(const unsigned* __restrict__ deg,
                                                    unsigned* __restrict__ off,
                                                    unsigned* __restrict__ cur,
                                                    float* __restrict__ dinv, int N) {
    const int t = threadIdx.x, lane = t & 63, wid = t >> 6;
    const int N4 = (N + 3) >> 2;
    __shared__ unsigned wsum[16];
    __shared__ unsigned carry_s;
    if (t == 0) carry_s = 0;
    __syncthreads();
    for (int base = 0; base < N4; base += 1024) {
        int i = base + t;
        unsigned d0 = 0, d1 = 0, d2 = 0, d3 = 0;
        if (4 * i + 3 < N) {
            uint4 d = reinterpret_cast<const uint4*>(deg)[i];
            d0 = d.x; d1 = d.y; d2 = d.z; d3 = d.w;
        } else if (4 * i < N) {
            d0 = deg[4 * i];
            if (4 * i + 1 < N) d1 = deg[4 * i + 1];
            if (4 * i + 2 < N) d2 = deg[4 * i + 2];
        }
        unsigned tsum = d0 + d1 + d2 + d3;
        unsigned v = tsum;
#pragma unroll
        for (int o = 1; o < 64; o <<= 1) {
            unsigned u = __shfl_up(v, o);
            if (lane >= o) v += u;
        }
        if (lane == 63) wsum[wid] = v;
        __syncthreads();
        if (wid == 0) {
            unsigned w = (lane < 16) ? wsum[lane] : 0u;
#pragma unroll
            for (int o = 1; o < 16; o <<= 1) {
                unsigned u = __shfl_up(w, o);
                if (lane >= o) w += u;
            }
            if (lane < 16) wsum[lane] = w;
        }
        __syncthreads();
        unsigned excl = carry_s + (wid ? wsum[wid - 1] : 0u) + (v - tsum);
        unsigned o0 = excl, o1 = o0 + d0, o2 = o1 + d1, o3 = o2 + d2;
        if (4 * i + 3 < N) {
            reinterpret_cast<uint4*>(off)[i] = make_uint4(o0, o1, o2, o3);
            reinterpret_cast<uint4*>(cur)[i] = make_uint4(o0, o1, o2, o3);
            reinterpret_cast<float4*>(dinv)[i] =
                make_float4(rsqrtf((float)d0 + 1.f), rsqrtf((float)d1 + 1.f),
                            rsqrtf((float)d2 + 1.f), rsqrtf((float)d3 + 1.f));
        } else if (4 * i < N) {
            off[4 * i] = o0; cur[4 * i] = o0; dinv[4 * i] = rsqrtf((float)d0 + 1.f);
            if (4 * i + 1 < N) { off[4 * i + 1] = o1; cur[4 * i + 1] = o1; dinv[4 * i + 1] = rsqrtf((float)d1 + 1.f); }
            if (4 * i + 2 < N) { off[4 * i + 2] = o2; cur[4 * i + 2] = o2; dinv[4 * i + 2] = rsqrtf((float)d2 + 1.f); }
        }
        __syncthreads();
        if (t == 0) carry_s += wsum[15];
        __syncthreads();
    }
    if (t == 0) off[N] = carry_s;
}

// ---------------- scatter edges into CSR (by col); stores source rows ----------------
__global__ void scatter_k(const int* __restrict__ row, const int* __restrict__ col,
                          unsigned* __restrict__ cur, int* __restrict__ srow, int E) {
    int e = blockIdx.x * blockDim.x + threadIdx.x;
    if (e < E) {
        unsigned p = atomicAdd(&cur[col[e]], 1u);
        srow[p] = row[e];
    }
}

// ---------------- GEMM partial: 2 rows/thread, W-chunk in LDS ----------------
// P[ch][r][:] = X[r, chunk] @ Wf[chunk, :]; 8 FMA per ds_read_b128.
__global__ __launch_bounds__(256) void gemm_v7(const float* __restrict__ X,
                                               const float* __restrict__ Wf,
                                               float* __restrict__ P, int N) {
    __shared__ float Ws[PERQ * 4 * DIM_OUT];        // 20480 B
    const int tid = threadIdx.x;
    const int ch  = blockIdx.y;
    const int q0  = ch * PERQ;
    const int cnt = min(NQ4 - q0, PERQ);            // 32,32,32,29

    {   // stage W chunk, zero-padded to PERQ
        const float4* wsrc = reinterpret_cast<const float4*>(Wf + (size_t)q0 * 4 * DIM_OUT);
        for (int i = tid; i < PERQ * DIM_OUT; i += 256)
            reinterpret_cast<float4*>(Ws)[i] =
                (i < cnt * DIM_OUT) ? wsrc[i] : make_float4(0.f, 0.f, 0.f, 0.f);
    }
    __syncthreads();

    const int r0 = blockIdx.x * 512 + tid;
    const int r1 = r0 + 256;
    if (r0 >= N) return;
    const bool has1 = (r1 < N);
    const float4* xa = reinterpret_cast<const float4*>(X + (size_t)r0 * DIM_IN) + q0;
    const float4* xb = reinterpret_cast<const float4*>(X + (size_t)(has1 ? r1 : r0) * DIM_IN) + q0;
    auto lda = [&](int q) { return xa[(q < cnt) ? q : 0]; };
    auto ldb = [&](int q) { return xb[(q < cnt) ? q : 0]; };

    float acc0[DIM_OUT], acc1[DIM_OUT];
#pragma unroll
    for (int j = 0; j < DIM_OUT; ++j) { acc0[j] = 0.f; acc1[j] = 0.f; }

    float4 ca0 = lda(0), ca1 = lda(1), ca2 = lda(2), ca3 = lda(3);
    float4 cb0 = ldb(0), cb1 = ldb(1), cb2 = ldb(2), cb3 = ldb(3);
    for (int m = 0; m < PERQ; m += 4) {             // 8 macro-iters
        float4 na0 = lda(m + 4), na1 = lda(m + 5), na2 = lda(m + 6), na3 = lda(m + 7);
        float4 nb0 = ldb(m + 4), nb1 = ldb(m + 5), nb2 = ldb(m + 6), nb3 = ldb(m + 7);
#pragma unroll
        for (int qq = 0; qq < 4; ++qq) {
            const float4 xva = (qq == 0) ? ca0 : (qq == 1) ? ca1 : (qq == 2) ? ca2 : ca3;
            const float4 xvb = (qq == 0) ? cb0 : (qq == 1) ? cb1 : (qq == 2) ? cb2 : cb3;
            const float* w = Ws + (m + qq) * 4 * DIM_OUT;
#pragma unroll
            for (int kk = 0; kk < 4; ++kk) {
                const float av = (kk == 0) ? xva.x : (kk == 1) ? xva.y : (kk == 2) ? xva.z : xva.w;
                const float bv = (kk == 0) ? xvb.x : (kk == 1) ? xvb.y : (kk == 2) ? xvb.z : xvb.w;
                const float* wk = w + kk * DIM_OUT;
#pragma unroll
                for (int j4 = 0; j4 < DIM_OUT / 4; ++j4) {
                    float4 wv = *reinterpret_cast<const float4*>(wk + j4 * 4);  // LDS broadcast
                    acc0[4 * j4]     = fmaf(av, wv.x, acc0[4 * j4]);
                    acc0[4 * j4 + 1] = fmaf(av, wv.y, acc0[4 * j4 + 1]);
                    acc0[4 * j4 + 2] = fmaf(av, wv.z, acc0[4 * j4 + 2]);
                    acc0[4 * j4 + 3] = fmaf(av, wv.w, acc0[4 * j4 + 3]);
                    acc1[4 * j4]     = fmaf(bv, wv.x, acc1[4 * j4]);
                    acc1[4 * j4 + 1] = fmaf(bv, wv.y, acc1[4 * j4 + 1]);
                    acc1[4 * j4 + 2] = fmaf(bv, wv.z, acc1[4 * j4 + 2]);
                    acc1[4 * j4 + 3] = fmaf(bv, wv.w, acc1[4 * j4 + 3]);
                }
            }
        }
        ca0 = na0; ca1 = na1; ca2 = na2; ca3 = na3;
        cb0 = nb0; cb1 = nb1; cb2 = nb2; cb3 = nb3;
    }

    float4* plane = reinterpret_cast<float4*>(P + (size_t)ch * N * DIM_OUT);
#pragma unroll
    for (int v = 0; v < DIM_OUT / 4; ++v)
        plane[(size_t)r0 * (DIM_OUT / 4) + v] =
            make_float4(acc0[4 * v], acc0[4 * v + 1], acc0[4 * v + 2], acc0[4 * v + 3]);
    if (has1) {
#pragma unroll
        for (int v = 0; v < DIM_OUT / 4; ++v)
            plane[(size_t)r1 * (DIM_OUT / 4) + v] =
                make_float4(acc1[4 * v], acc1[4 * v + 1], acc1[4 * v + 2], acc1[4 * v + 3]);
    }
}

// ------- reduce partials, scale by dinv, pack to bf16: Gb[r] = bf16(dinv[r]*sum P) -------
__global__ __launch_bounds__(256) void reduce_pack(const float* __restrict__ P,
                                                   const float* __restrict__ dinv,
                                                   uint4* __restrict__ Gb, int N) {
    int idx = blockIdx.x * blockDim.x + threadIdx.x;      // over N*5 uint4s
    if (idx >= N * ROWU4) return;
    int r = idx / ROWU4;
    int v = idx - r * ROWU4;                              // 8-dim group
    const size_t plane = (size_t)N * (DIM_OUT / 4);
    const float4* p = reinterpret_cast<const float4*>(P) + (size_t)r * (DIM_OUT / 4) + 2 * v;
    float4 s0 = p[0], s1 = p[1];
#pragma unroll
    for (int c = 1; c < NCH; ++c) {
        float4 u0 = p[c * plane], u1 = p[c * plane + 1];
        s0.x += u0.x; s0.y += u0.y; s0.z += u0.z; s0.w += u0.w;
        s1.x += u1.x; s1.y += u1.y; s1.z += u1.z; s1.w += u1.w;
    }
    float d = dinv[r];
    Gb[idx] = make_uint4(bf_pair(d * s0.x, d * s0.y), bf_pair(d * s0.z, d * s0.w),
                         bf_pair(d * s1.x, d * s1.y), bf_pair(d * s1.z, d * s1.w));
}

// ---------------- aggregation over packed bf16 rows: 5 threads/node ----------------
// FINAL=0: outb[c] = bf16( d*(d*acc + bias) )    FINAL=1: outf[c] = d*acc (fp32)
template <int FINAL>
__global__ __launch_bounds__(256) void agg_bf(const unsigned* __restrict__ off,
                                              const int* __restrict__ srow,
                                              const float* __restrict__ dinv,
                                              const uint4* __restrict__ Gb,
                                              const float* __restrict__ bias,
                                              uint4* __restrict__ outb,
                                              float4* __restrict__ outf, int N) {
    const int idx = blockIdx.x * blockDim.x + threadIdx.x;
    if (idx >= N * ROWU4) return;
    const int c = idx / ROWU4;
    const int v = idx - c * ROWU4;
    const unsigned beg = off[c], end = off[c + 1];

    float a[8], b[8];
    {   // self loop
        uint4 s = Gb[(size_t)c * ROWU4 + v];
        bf_unpack(s.x, a[0], a[1]); bf_unpack(s.y, a[2], a[3]);
        bf_unpack(s.z, a[4], a[5]); bf_unpack(s.w, a[6], a[7]);
    }
#pragma unroll
    for (int j = 0; j < 8; ++j) b[j] = 0.f;

    unsigned e = beg;
    for (; e + 4 <= end; e += 4) {                   // 4 gathers in flight per lane
        int r0 = srow[e], r1 = srow[e + 1], r2 = srow[e + 2], r3 = srow[e + 3];
        uint4 g0 = Gb[(size_t)r0 * ROWU4 + v];
        uint4 g1 = Gb[(size_t)r1 * ROWU4 + v];
        uint4 g2 = Gb[(size_t)r2 * ROWU4 + v];
        uint4 g3 = Gb[(size_t)r3 * ROWU4 + v];
        float t0, t1;
        bf_unpack(g0.x, t0, t1); a[0] += t0; a[1] += t1;
        bf_unpack(g0.y, t0, t1); a[2] += t0; a[3] += t1;
        bf_unpack(g0.z, t0, t1); a[4] += t0; a[5] += t1;
        bf_unpack(g0.w, t0, t1); a[6] += t0; a[7] += t1;
        bf_unpack(g1.x, t0, t1); b[0] += t0; b[1] += t1;
        bf_unpack(g1.y, t0, t1); b[2] += t0; b[3] += t1;
        bf_unpack(g1.z, t0, t1); b[4] += t0; b[5] += t1;
        bf_unpack(g1.w, t0, t1); b[6] += t0; b[7] += t1;
        bf_unpack(g2.x, t0, t1); a[0] += t0; a[1] += t1;
        bf_unpack(g2.y, t0, t1); a[2] += t0; a[3] += t1;
        bf_unpack(g2.z, t0, t1); a[4] += t0; a[5] += t1;
        bf_unpack(g2.w, t0, t1); a[6] += t0; a[7] += t1;
        bf_unpack(g3.x, t0, t1); b[0] += t0; b[1] += t1;
        bf_unpack(g3.y, t0, t1); b[2] += t0; b[3] += t1;
        bf_unpack(g3.z, t0, t1); b[4] += t0; b[5] += t1;
        bf_unpack(g3.w, t0, t1); b[6] += t0; b[7] += t1;
    }
    for (; e < end; ++e) {
        uint4 g = Gb[(size_t)srow[e] * ROWU4 + v];
        float t0, t1;
        bf_unpack(g.x, t0, t1); a[0] += t0; a[1] += t1;
        bf_unpack(g.y, t0, t1); a[2] += t0; a[3] += t1;
        bf_unpack(g.z, t0, t1); a[4] += t0; a[5] += t1;
        bf_unpack(g.w, t0, t1); a[6] += t0; a[7] += t1;
    }
    const float d = dinv[c];
    float h[8];
#pragma unroll
    for (int j = 0; j < 8; ++j) h[j] = a[j] + b[j];

    if (!FINAL) {
        const float* bp = bias + v * 8;
#pragma unroll
        for (int j = 0; j < 8; ++j) h[j] = d * fmaf(d, h[j], bp[j]);
        outb[idx] = make_uint4(bf_pair(h[0], h[1]), bf_pair(h[2], h[3]),
                               bf_pair(h[4], h[5]), bf_pair(h[6], h[7]));
    } else {
#pragma unroll
        for (int j = 0; j < 8; ++j) h[j] *= d;
        outf[(size_t)c * (DIM_OUT / 4) + 2 * v]     = make_float4(h[0], h[1], h[2], h[3]);
        outf[(size_t)c * (DIM_OUT / 4) + 2 * v + 1] = make_float4(h[4], h[5], h[6], h[7]);
    }
}

// ---------------- log_softmax over 40 (wave per row) + final bias b3 ----------------
__global__ void logsoftmax40(const float* __restrict__ Hin, const float* __restrict__ b3,
                             float* __restrict__ out, int N) {
    int wave = (blockIdx.x * blockDim.x + threadIdx.x) >> 6;
    int lane = threadIdx.x & 63;
    if (wave >= N) return;
    float x = 0.f, v = -INFINITY;
    if (lane < DIM_OUT) {
        x = Hin[(size_t)wave * DIM_OUT + lane] + b3[lane];
        v = x;
    }
#pragma unroll
    for (int o = 32; o; o >>= 1) v = fmaxf(v, __shfl_xor(v, o));
    float ex = (lane < DIM_OUT) ? expf(x - v) : 0.f;
    float s = ex;
#pragma unroll
    for (int o = 32; o; o >>= 1) s += __shfl_xor(s, o);
    if (lane < DIM_OUT) out[(size_t)wave * DIM_OUT + lane] = x - v - logf(s);
}

// ---------------- launch ----------------
extern "C" void kernel_launch(void* const* d_in, const int* in_sizes, int n_in,
                              void* d_out, int out_size, void* d_ws, size_t ws_size,
                              hipStream_t stream) {
    const float* x  = (const float*)d_in[0];
    const int*   ei = (const int*)d_in[1];
    const float* W1 = (const float*)d_in[2];
    const float* b1 = (const float*)d_in[3];
    const float* W2 = (const float*)d_in[4];
    const float* b2 = (const float*)d_in[5];
    const float* W3 = (const float*)d_in[6];
    const float* b3 = (const float*)d_in[7];
    float* out = (float*)d_out;

    const int N = in_sizes[0] / DIM_IN;
    const int E = in_sizes[1] / 2;
    const int* row = ei;       // edge_index[0]
    const int* col = ei + E;   // edge_index[1]

    char* wsp = (char*)d_ws;
    size_t used = 0;
    auto alloc = [&](size_t bytes) -> void* {
        void* p = wsp + used;
        used += (bytes + 255) & ~(size_t)255;
        return p;
    };
    unsigned* deg  = (unsigned*)alloc((size_t)N * 4);
    unsigned* off  = (unsigned*)alloc((size_t)(N + 1) * 4);
    unsigned* cur  = (unsigned*)alloc((size_t)N * 4);
    int*      srow = (int*)alloc((size_t)E * 4);
    float*    dinv = (float*)alloc((size_t)N * 4);
    float*    W23  = (float*)alloc((size_t)DIM_HID * DIM_OUT * 4);
    float*    Wf   = (float*)alloc((size_t)DIM_IN * DIM_OUT * 4);
    float*    bp1  = (float*)alloc((size_t)DIM_OUT * 4);
    float*    bp2  = (float*)alloc((size_t)DIM_OUT * 4);
    uint4*    Gb0  = (uint4*)alloc((size_t)N * ROWU4 * 16);
    uint4*    Gb1  = (uint4*)alloc((size_t)N * ROWU4 * 16);
    float*    H    = (float*)alloc((size_t)N * DIM_OUT * 4 + 256);
    float*    P    = (float*)alloc((size_t)NCH * N * DIM_OUT * 4 + 256);

    // ---- CSR build + normalization ----
    hipMemsetAsync(deg, 0, (size_t)N * 4, stream);
    degree_k<<<(E + 255) / 256, 256, 0, stream>>>(col, deg, E);
    scan_block4<<<1, 1024, 0, stream>>>(deg, off, cur, dinv, N);
    scatter_k<<<(E + 255) / 256, 256, 0, stream>>>(row, col, cur, srow, E);

    // ---- weight fusion (small-first association): W23 = W2@W3; Wf = W1@W23 ----
    mm_small<<<(DIM_HID * DIM_OUT + 255) / 256, 256, 0, stream>>>(W2, W3, W23, DIM_HID, DIM_HID, DIM_OUT);
    mm_small<<<(DIM_IN * DIM_OUT + 255) / 256, 256, 0, stream>>>(W1, W23, Wf, DIM_IN, DIM_HID, DIM_OUT);
    bias_fuse<<<1, 2 * DIM_OUT + 48, 0, stream>>>(b1, W23, b2, W3, bp1, bp2);

    // ---- Gb0 = bf16( dinv .* (X @ Wf) ) via 4 K-chunk partials + reduce ----
    {
        dim3 grid((N + 511) / 512, NCH);
        gemm_v7<<<grid, 256, 0, stream>>>(x, Wf, P, N);
        reduce_pack<<<(N * ROWU4 + 255) / 256, 256, 0, stream>>>(P, dinv, Gb0, N);
    }

    // ---- three aggregations over packed bf16 features ----
    const int aggGrid = (N * ROWU4 + 255) / 256;
    agg_bf<0><<<aggGrid, 256, 0, stream>>>(off, srow, dinv, Gb0, bp1, Gb1, nullptr, N);
    agg_bf<0><<<aggGrid, 256, 0, stream>>>(off, srow, dinv, Gb1, bp2, Gb0, nullptr, N);
    agg_bf<1><<<aggGrid, 256, 0, stream>>>(off, srow, dinv, Gb0, nullptr, nullptr, (float4*)H, N);

    // ---- out = log_softmax(H + b3) ----
    logsoftmax40<<<(N + 3) / 4, 256, 0, stream>>>(H, b3, out, N);
}

// Round 8
// 341.790 us; speedup vs baseline: 1.7418x; 1.1185x over previous
//
#include <hip/hip_runtime.h>
#include <math.h>

#define DIM_IN  500
#define DIM_HID 128
#define DIM_OUT 40
#define WROWS   48    // padded cols of Wf (3 x 16)
#define WK      520   // padded K (512) + 8 pad for LDS bank spread

typedef __attribute__((ext_vector_type(8))) short short8_t;
typedef __attribute__((ext_vector_type(4))) float f32x4;

union U4S8 { uint4 u; short8_t s; };

// ---- bf16 helpers (RNE) ----
__device__ __forceinline__ unsigned bf_pair(float a, float b) {
    unsigned ua = __float_as_uint(a);
    unsigned ub = __float_as_uint(b);
    ua = (ua + 0x7FFFu + ((ua >> 16) & 1u)) >> 16;          // low 16
    ub = (ub + 0x7FFFu + ((ub >> 16) & 1u)) & 0xFFFF0000u;  // high 16
    return ua | ub;
}
__device__ __forceinline__ unsigned short bf1(float x) {
    unsigned u = __float_as_uint(x);
    return (unsigned short)((u + 0x7FFFu + ((u >> 16) & 1u)) >> 16);
}
__device__ __forceinline__ void bf_unpack(unsigned u, float& lo, float& hi) {
    lo = __uint_as_float(u << 16);
    hi = __uint_as_float(u & 0xFFFF0000u);
}
__device__ __forceinline__ short8_t pack8(float4 a, float4 b) {
    U4S8 r;
    r.u.x = bf_pair(a.x, a.y); r.u.y = bf_pair(a.z, a.w);
    r.u.z = bf_pair(b.x, b.y); r.u.w = bf_pair(b.z, b.w);
    return r.s;
}

// ---------------- small generic matmul (weight fusion, tiny) ----------------
__global__ void mm_small(const float* __restrict__ A, const float* __restrict__ B,
                         float* __restrict__ C, int M, int K, int Nc) {
    int idx = blockIdx.x * blockDim.x + threadIdx.x;
    if (idx >= M * Nc) return;
    int i = idx / Nc, j = idx - i * Nc;
    const float* a = A + (size_t)i * K;
    const float* b = B + j;
    float s0 = 0.f, s1 = 0.f, s2 = 0.f, s3 = 0.f;
    int k = 0;
    for (; k + 4 <= K; k += 4) {
        s0 = fmaf(a[k],     b[(size_t)k * Nc],       s0);
        s1 = fmaf(a[k + 1], b[(size_t)(k + 1) * Nc], s1);
        s2 = fmaf(a[k + 2], b[(size_t)(k + 2) * Nc], s2);
        s3 = fmaf(a[k + 3], b[(size_t)(k + 3) * Nc], s3);
    }
    for (; k < K; ++k) s0 = fmaf(a[k], b[(size_t)k * Nc], s0);
    C[idx] = (s0 + s1) + (s2 + s3);
}

// bp1 = b1 @ W23 (K=128), bp2 = b2 @ W3 (K=128)
__global__ void bias_fuse(const float* __restrict__ b1, const float* __restrict__ W23,
                          const float* __restrict__ b2, const float* __restrict__ W3,
                          float* __restrict__ bp1, float* __restrict__ bp2) {
    int t = threadIdx.x;
    if (t < DIM_OUT) {
        float s = 0.f;
        for (int k = 0; k < DIM_HID; ++k) s = fmaf(b1[k], W23[k * DIM_OUT + t], s);
        bp1[t] = s;
    } else if (t < 2 * DIM_OUT) {
        int j = t - DIM_OUT;
        float s = 0.f;
        for (int k = 0; k < DIM_HID; ++k) s = fmaf(b2[k], W3[k * DIM_OUT + j], s);
        bp2[j] = s;
    }
}

// ---- build WfT bf16 [48][520]: WfT[j][k] = bf16( (W1 @ W23)[k][j] ), zero-padded ----
__global__ void wft_build(const float* __restrict__ W1, const float* __restrict__ W23,
                          unsigned short* __restrict__ WfT) {
    int idx = blockIdx.x * blockDim.x + threadIdx.x;
    if (idx >= WROWS * WK) return;
    int j = idx / WK;
    int k = idx - j * WK;
    float s = 0.f;
    if (j < DIM_OUT && k < DIM_IN) {
        const float* a = W1 + (size_t)k * DIM_HID;
        const float* b = W23 + j;
        float s0 = 0.f, s1 = 0.f, s2 = 0.f, s3 = 0.f;
        for (int h = 0; h < DIM_HID; h += 4) {
            s0 = fmaf(a[h],     b[(size_t)h * DIM_OUT],       s0);
            s1 = fmaf(a[h + 1], b[(size_t)(h + 1) * DIM_OUT], s1);
            s2 = fmaf(a[h + 2], b[(size_t)(h + 2) * DIM_OUT], s2);
            s3 = fmaf(a[h + 3], b[(size_t)(h + 3) * DIM_OUT], s3);
        }
        s = (s0 + s1) + (s2 + s3);
    }
    WfT[idx] = bf1(s);
}

// ---------------- degree histogram (in-degree over col) ----------------
__global__ void degree_k(const int* __restrict__ col, unsigned* __restrict__ deg, int E) {
    int e = blockIdx.x * blockDim.x + threadIdx.x;
    if (e < E) atomicAdd(&deg[col[e]], 1u);
}

// ---------------- single-block exclusive scan (4 elems/thread) + dinv ----------------
__global__ __launch_bounds__(1024) void scan_block4(const unsigned* __restrict__ deg,
                                                    unsigned* __restrict__ off,
                                                    unsigned* __restrict__ cur,
                                                    float* __restrict__ dinv, int N) {
    const int t = threadIdx.x, lane = t & 63, wid = t >> 6;
    const int N4 = (N + 3) >> 2;
    __shared__ unsigned wsum[16];
    __shared__ unsigned carry_s;
    if (t == 0) carry_s = 0;
    __syncthreads();
    for (int base = 0; base < N4; base += 1024) {
        int i = base + t;
        unsigned d0 = 0, d1 = 0, d2 = 0, d3 = 0;
        if (4 * i + 3 < N) {
            uint4 d = reinterpret_cast<const uint4*>(deg)[i];
            d0 = d.x; d1 = d.y; d2 = d.z; d3 = d.w;
        } else if (4 * i < N) {
            d0 = deg[4 * i];
            if (4 * i + 1 < N) d1 = deg[4 * i + 1];
            if (4 * i + 2 < N) d2 = deg[4 * i + 2];
        }
        unsigned tsum = d0 + d1 + d2 + d3;
        unsigned v = tsum;
#pragma unroll
        for (int o = 1; o < 64; o <<= 1) {
            unsigned u = __shfl_up(v, o);
            if (lane >= o) v += u;
        }
        if (lane == 63) wsum[wid] = v;
        __syncthreads();
        if (wid == 0) {
            unsigned w = (lane < 16) ? wsum[lane] : 0u;
#pragma unroll
            for (int o = 1; o < 16; o <<= 1) {
                unsigned u = __shfl_up(w, o);
                if (lane >= o) w += u;
            }
            if (lane < 16) wsum[lane] = w;
        }
        __syncthreads();
        unsigned excl = carry_s + (wid ? wsum[wid - 1] : 0u) + (v - tsum);
        unsigned o0 = excl, o1 = o0 + d0, o2 = o1 + d1, o3 = o2 + d2;
        if (4 * i + 3 < N) {
            reinterpret_cast<uint4*>(off)[i] = make_uint4(o0, o1, o2, o3);
            reinterpret_cast<uint4*>(cur)[i] = make_uint4(o0, o1, o2, o3);
            reinterpret_cast<float4*>(dinv)[i] =
                make_float4(rsqrtf((float)d0 + 1.f), rsqrtf((float)d1 + 1.f),
                            rsqrtf((float)d2 + 1.f), rsqrtf((float)d3 + 1.f));
        } else if (4 * i < N) {
            off[4 * i] = o0; cur[4 * i] = o0; dinv[4 * i] = rsqrtf((float)d0 + 1.f);
            if (4 * i + 1 < N) { off[4 * i + 1] = o1; cur[4 * i + 1] = o1; dinv[4 * i + 1] = rsqrtf((float)d1 + 1.f); }
            if (4 * i + 2 < N) { off[4 * i + 2] = o2; cur[4 * i + 2] = o2; dinv[4 * i + 2] = rsqrtf((float)d2 + 1.f); }
        }
        __syncthreads();
        if (t == 0) carry_s += wsum[15];
        __syncthreads();
    }
    if (t == 0) off[N] = carry_s;
}

// ---------------- scatter edges into CSR (by col); stores source rows ----------------
__global__ void scatter_k(const int* __restrict__ row, const int* __restrict__ col,
                          unsigned* __restrict__ cur, int* __restrict__ srow, int E) {
    int e = blockIdx.x * blockDim.x + threadIdx.x;
    if (e < E) {
        unsigned p = atomicAdd(&cur[col[e]], 1u);
        srow[p] = row[e];
    }
}

// ---------------- MFMA GEMM: Gb[r][j] = bf16( dinv[r] * (X @ Wf)[r][j] ) ----------------
// wave = one 16-row tile; 3 col-tiles of 16 (40 real); K 500->512 zero-padded in WfT.
__global__ __launch_bounds__(256) void gemm_mfma(const float* __restrict__ X,
                                                 const unsigned short* __restrict__ WfT,
                                                 const float* __restrict__ dinv,
                                                 unsigned short* __restrict__ Gb,
                                                 int N, int ntiles) {
    __shared__ uint4 Ws[WROWS * WK / 8];            // 3120 uint4 = 49920 B
    const int tid = threadIdx.x;
    {
        const uint4* wsrc = reinterpret_cast<const uint4*>(WfT);
        for (int i = tid; i < WROWS * WK / 8; i += 256) Ws[i] = wsrc[i];
    }
    __syncthreads();

    const int tile = blockIdx.x * 4 + (tid >> 6);
    if (tile >= ntiles) return;
    const int lane = tid & 63;
    const int r0w  = tile * 16;
    const int rloc = lane & 15;
    const int kgrp = lane >> 4;                     // 0..3
    const int rowA = min(r0w + rloc, N - 1);
    const float* xrow = X + (size_t)rowA * DIM_IN;

    f32x4 acc0 = {0.f, 0.f, 0.f, 0.f};
    f32x4 acc1 = {0.f, 0.f, 0.f, 0.f};
    f32x4 acc2 = {0.f, 0.f, 0.f, 0.f};

#pragma unroll 4
    for (int k0 = 0; k0 < 512; k0 += 32) {
        const int kb = k0 + kgrp * 8;
        const int c1 = min(kb, 496);                // clamp: values beyond K=500 hit zero B rows
        const int c2 = min(kb + 4, 496);
        float4 xa = *reinterpret_cast<const float4*>(xrow + c1);
        float4 xb = *reinterpret_cast<const float4*>(xrow + c2);
        short8_t afrag = pack8(xa, xb);

        const int kq = kb >> 3;                     // uint4 index along K
        U4S8 b0, b1, b2;
        b0.u = Ws[(0  + rloc) * (WK / 8) + kq];
        b1.u = Ws[(16 + rloc) * (WK / 8) + kq];
        b2.u = Ws[(32 + rloc) * (WK / 8) + kq];

        acc0 = __builtin_amdgcn_mfma_f32_16x16x32_bf16(afrag, b0.s, acc0, 0, 0, 0);
        acc1 = __builtin_amdgcn_mfma_f32_16x16x32_bf16(afrag, b1.s, acc1, 0, 0, 0);
        acc2 = __builtin_amdgcn_mfma_f32_16x16x32_bf16(afrag, b2.s, acc2, 0, 0, 0);
    }

    // epilogue: C layout col = lane&15, row = (lane>>4)*4 + i  [m89]
#pragma unroll
    for (int i = 0; i < 4; ++i) {
        const int rg = r0w + kgrp * 4 + i;
        if (rg >= N) continue;
        const float d = dinv[rg];
        unsigned short* gr = Gb + (size_t)rg * DIM_OUT;
        gr[rloc]      = bf1(acc0[i] * d);           // cols 0-15
        gr[16 + rloc] = bf1(acc1[i] * d);           // cols 16-31
        if (rloc < 8) gr[32 + rloc] = bf1(acc2[i] * d);  // cols 32-39 (40-47 dropped)
    }
}

// ---------------- aggregation: 10 threads/node, uint2 (4-dim) gathers ----------------
// FINAL=0: outb = bf16( d*(d*acc + bias) )    FINAL=1: outf = d*acc (fp32)
template <int FINAL>
__global__ __launch_bounds__(256) void agg_bf(const unsigned* __restrict__ off,
                                              const int* __restrict__ srow,
                                              const float* __restrict__ dinv,
                                              const uint2* __restrict__ Gb2,
                                              const float4* __restrict__ bias4,
                                              uint2* __restrict__ outb,
                                              float4* __restrict__ outf, int N) {
    const int idx = blockIdx.x * blockDim.x + threadIdx.x;
    if (idx >= N * 10) return;
    const int c = idx / 10;
    const int v = idx - c * 10;
    const unsigned beg = off[c], end = off[c + 1];

    float a0, a1, a2, a3, f0, f1, f2, f3;
    {
        uint2 s = Gb2[(size_t)c * 10 + v];          // self loop
        bf_unpack(s.x, a0, a1);
        bf_unpack(s.y, a2, a3);
    }
    f0 = f1 = f2 = f3 = 0.f;
    float t0, t1;

    unsigned e = beg;
    unsigned ea = (beg + 3u) & ~3u; if (ea > end) ea = end;
    for (; e < ea; ++e) {                           // peel to 16B-aligned index reads
        uint2 g = Gb2[(size_t)(unsigned)srow[e] * 10 + v];
        bf_unpack(g.x, t0, t1); a0 += t0; a1 += t1;
        bf_unpack(g.y, t0, t1); a2 += t0; a3 += t1;
    }
    for (; e + 8 <= end; e += 8) {                  // 2 vec index loads + 8 gathers in flight
        uint4 i0 = *reinterpret_cast<const uint4*>(srow + e);
        uint4 i1 = *reinterpret_cast<const uint4*>(srow + e + 4);
        uint2 g0 = Gb2[(size_t)i0.x * 10 + v];
        uint2 g1 = Gb2[(size_t)i0.y * 10 + v];
        uint2 g2 = Gb2[(size_t)i0.z * 10 + v];
        uint2 g3 = Gb2[(size_t)i0.w * 10 + v];
        uint2 g4 = Gb2[(size_t)i1.x * 10 + v];
        uint2 g5 = Gb2[(size_t)i1.y * 10 + v];
        uint2 g6 = Gb2[(size_t)i1.z * 10 + v];
        uint2 g7 = Gb2[(size_t)i1.w * 10 + v];
        bf_unpack(g0.x, t0, t1); a0 += t0; a1 += t1; bf_unpack(g0.y, t0, t1); a2 += t0; a3 += t1;
        bf_unpack(g1.x, t0, t1); f0 += t0; f1 += t1; bf_unpack(g1.y, t0, t1); f2 += t0; f3 += t1;
        bf_unpack(g2.x, t0, t1); a0 += t0; a1 += t1; bf_unpack(g2.y, t0, t1); a2 += t0; a3 += t1;
        bf_unpack(g3.x, t0, t1); f0 += t0; f1 += t1; bf_unpack(g3.y, t0, t1); f2 += t0; f3 += t1;
        bf_unpack(g4.x, t0, t1); a0 += t0; a1 += t1; bf_unpack(g4.y, t0, t1); a2 += t0; a3 += t1;
        bf_unpack(g5.x, t0, t1); f0 += t0; f1 += t1; bf_unpack(g5.y, t0, t1); f2 += t0; f3 += t1;
        bf_unpack(g6.x, t0, t1); a0 += t0; a1 += t1; bf_unpack(g6.y, t0, t1); a2 += t0; a3 += t1;
        bf_unpack(g7.x, t0, t1); f0 += t0; f1 += t1; bf_unpack(g7.y, t0, t1); f2 += t0; f3 += t1;
    }
    if (e + 4 <= end) {
        uint4 i0 = *reinterpret_cast<const uint4*>(srow + e);
        uint2 g0 = Gb2[(size_t)i0.x * 10 + v];
        uint2 g1 = Gb2[(size_t)i0.y * 10 + v];
        uint2 g2 = Gb2[(size_t)i0.z * 10 + v];
        uint2 g3 = Gb2[(size_t)i0.w * 10 + v];
        bf_unpack(g0.x, t0, t1); a0 += t0; a1 += t1; bf_unpack(g0.y, t0, t1); a2 += t0; a3 += t1;
        bf_unpack(g1.x, t0, t1); f0 += t0; f1 += t1; bf_unpack(g1.y, t0, t1); f2 += t0; f3 += t1;
        bf_unpack(g2.x, t0, t1); a0 += t0; a1 += t1; bf_unpack(g2.y, t0, t1); a2 += t0; a3 += t1;
        bf_unpack(g3.x, t0, t1); f0 += t0; f1 += t1; bf_unpack(g3.y, t0, t1); f2 += t0; f3 += t1;
        e += 4;
    }
    for (; e < end; ++e) {
        uint2 g = Gb2[(size_t)(unsigned)srow[e] * 10 + v];
        bf_unpack(g.x, t0, t1); a0 += t0; a1 += t1;
        bf_unpack(g.y, t0, t1); a2 += t0; a3 += t1;
    }

    float h0 = a0 + f0, h1 = a1 + f1, h2 = a2 + f2, h3 = a3 + f3;
    const float d = dinv[c];
    if (!FINAL) {
        float4 bp = bias4[v];
        h0 = d * fmaf(d, h0, bp.x);
        h1 = d * fmaf(d, h1, bp.y);
        h2 = d * fmaf(d, h2, bp.z);
        h3 = d * fmaf(d, h3, bp.w);
        uint2 o;
        o.x = bf_pair(h0, h1);
        o.y = bf_pair(h2, h3);
        outb[(size_t)c * 10 + v] = o;
    } else {
        outf[(size_t)c * 10 + v] = make_float4(d * h0, d * h1, d * h2, d * h3);
    }
}

// ---------------- log_softmax over 40 (wave per row) + final bias b3 ----------------
__global__ void logsoftmax40(const float* __restrict__ Hin, const float* __restrict__ b3,
                             float* __restrict__ out, int N) {
    int wave = (blockIdx.x * blockDim.x + threadIdx.x) >> 6;
    int lane = threadIdx.x & 63;
    if (wave >= N) return;
    float x = 0.f, v = -INFINITY;
    if (lane < DIM_OUT) {
        x = Hin[(size_t)wave * DIM_OUT + lane] + b3[lane];
        v = x;
    }
#pragma unroll
    for (int o = 32; o; o >>= 1) v = fmaxf(v, __shfl_xor(v, o));
    float ex = (lane < DIM_OUT) ? expf(x - v) : 0.f;
    float s = ex;
#pragma unroll
    for (int o = 32; o; o >>= 1) s += __shfl_xor(s, o);
    if (lane < DIM_OUT) out[(size_t)wave * DIM_OUT + lane] = x - v - logf(s);
}

// ---------------- launch ----------------
extern "C" void kernel_launch(void* const* d_in, const int* in_sizes, int n_in,
                              void* d_out, int out_size, void* d_ws, size_t ws_size,
                              hipStream_t stream) {
    const float* x  = (const float*)d_in[0];
    const int*   ei = (const int*)d_in[1];
    const float* W1 = (const float*)d_in[2];
    const float* b1 = (const float*)d_in[3];
    const float* W2 = (const float*)d_in[4];
    const float* b2 = (const float*)d_in[5];
    const float* W3 = (const float*)d_in[6];
    const float* b3 = (const float*)d_in[7];
    float* out = (float*)d_out;

    const int N = in_sizes[0] / DIM_IN;
    const int E = in_sizes[1] / 2;
    const int* row = ei;       // edge_index[0]
    const int* col = ei + E;   // edge_index[1]

    char* wsp = (char*)d_ws;
    size_t used = 0;
    auto alloc = [&](size_t bytes) -> void* {
        void* p = wsp + used;
        used += (bytes + 255) & ~(size_t)255;
        return p;
    };
    unsigned*       deg   = (unsigned*)alloc((size_t)N * 4);
    unsigned*       off   = (unsigned*)alloc((size_t)(N + 1) * 4);
    unsigned*       cur   = (unsigned*)alloc((size_t)N * 4);
    int*            srow  = (int*)alloc((size_t)E * 4);
    float*          dinv  = (float*)alloc((size_t)N * 4);
    float*          W23   = (float*)alloc((size_t)DIM_HID * DIM_OUT * 4);
    unsigned short* WfT16 = (unsigned short*)alloc((size_t)WROWS * WK * 2);
    float*          bp1   = (float*)alloc((size_t)DIM_OUT * 4);
    float*          bp2   = (float*)alloc((size_t)DIM_OUT * 4);
    unsigned short* Gb0   = (unsigned short*)alloc((size_t)N * DIM_OUT * 2);
    unsigned short* Gb1   = (unsigned short*)alloc((size_t)N * DIM_OUT * 2);
    float*          H     = (float*)alloc((size_t)N * DIM_OUT * 4 + 256);

    // ---- CSR build + normalization ----
    hipMemsetAsync(deg, 0, (size_t)N * 4, stream);
    degree_k<<<(E + 255) / 256, 256, 0, stream>>>(col, deg, E);
    scan_block4<<<1, 1024, 0, stream>>>(deg, off, cur, dinv, N);
    scatter_k<<<(E + 255) / 256, 256, 0, stream>>>(row, col, cur, srow, E);

    // ---- weight fusion: W23 = W2@W3; WfT = bf16((W1@W23)^T) padded; fused biases ----
    mm_small<<<(DIM_HID * DIM_OUT + 255) / 256, 256, 0, stream>>>(W2, W3, W23, DIM_HID, DIM_HID, DIM_OUT);
    wft_build<<<(WROWS * WK + 255) / 256, 256, 0, stream>>>(W1, W23, WfT16);
    bias_fuse<<<1, 128, 0, stream>>>(b1, W23, b2, W3, bp1, bp2);

    // ---- Gb0 = bf16( dinv .* (X @ Wf) ) via MFMA ----
    {
        const int ntiles = (N + 15) / 16;
        gemm_mfma<<<(ntiles + 3) / 4, 256, 0, stream>>>(x, WfT16, dinv, Gb0, N, ntiles);
    }

    // ---- three aggregations (10 threads per node, 4 dims each) ----
    const int aggGrid = (N * 10 + 255) / 256;
    agg_bf<0><<<aggGrid, 256, 0, stream>>>(off, srow, dinv, (const uint2*)Gb0, (const float4*)bp1, (uint2*)Gb1, nullptr, N);
    agg_bf<0><<<aggGrid, 256, 0, stream>>>(off, srow, dinv, (const uint2*)Gb1, (const float4*)bp2, (uint2*)Gb0, nullptr, N);
    agg_bf<1><<<aggGrid, 256, 0, stream>>>(off, srow, dinv, (const uint2*)Gb0, nullptr, nullptr, (float4*)H, N);

    // ---- out = log_softmax(H + b3) ----
    logsoftmax40<<<(N + 3) / 4, 256, 0, stream>>>(H, b3, out, N);
}

// Round 9
// 336.672 us; speedup vs baseline: 1.7682x; 1.0152x over previous
//
#include <hip/hip_runtime.h>
#include <math.h>

#define DIM_IN  500
#define DIM_HID 128
#define DIM_OUT 40
#define WROWS   48     // padded cols of Wf (3 x 16)
#define WK      520    // padded K (512) + 8 bf16 pad
#define WKQ     65     // WK/8 (uint4 units per WfT row)
#define GSTR2   16     // Gb row stride in uint2 (128 B padded row)
#define GSTR    64     // Gb row stride in shorts

typedef __attribute__((ext_vector_type(8))) short short8_t;
typedef __attribute__((ext_vector_type(4))) float f32x4;

union U4S8 { uint4 u; short8_t s; };

// ---- bf16 helpers (RNE) ----
__device__ __forceinline__ unsigned bf_pair(float a, float b) {
    unsigned ua = __float_as_uint(a);
    unsigned ub = __float_as_uint(b);
    ua = (ua + 0x7FFFu + ((ua >> 16) & 1u)) >> 16;
    ub = (ub + 0x7FFFu + ((ub >> 16) & 1u)) & 0xFFFF0000u;
    return ua | ub;
}
__device__ __forceinline__ unsigned short bf1(float x) {
    unsigned u = __float_as_uint(x);
    return (unsigned short)((u + 0x7FFFu + ((u >> 16) & 1u)) >> 16);
}
__device__ __forceinline__ void bf_unpack(unsigned u, float& lo, float& hi) {
    lo = __uint_as_float(u << 16);
    hi = __uint_as_float(u & 0xFFFF0000u);
}
__device__ __forceinline__ short8_t pack8(float4 a, float4 b) {
    U4S8 r;
    r.u.x = bf_pair(a.x, a.y); r.u.y = bf_pair(a.z, a.w);
    r.u.z = bf_pair(b.x, b.y); r.u.w = bf_pair(b.z, b.w);
    return r.s;
}

// ---------------- fuse1: W23T[40][128] = (W2@W3)^T  +  bp2 = b2@W3 ----------------
__global__ __launch_bounds__(256) void fuse1(const float* __restrict__ W2,
                                             const float* __restrict__ W3,
                                             const float* __restrict__ b2,
                                             float* __restrict__ W23T,
                                             float* __restrict__ bp2) {
    int idx = blockIdx.x * blockDim.x + threadIdx.x;
    if (idx < DIM_OUT * DIM_HID) {
        int j = idx >> 7, h = idx & 127;                 // W23T[j][h]
        const float* a = W2 + (size_t)h * DIM_HID;       // contiguous
        float s0 = 0.f, s1 = 0.f, s2 = 0.f, s3 = 0.f;
#pragma unroll 4
        for (int g = 0; g < DIM_HID; g += 4) {
            s0 = fmaf(a[g],     W3[(size_t)g * DIM_OUT + j],       s0);
            s1 = fmaf(a[g + 1], W3[(size_t)(g + 1) * DIM_OUT + j], s1);
            s2 = fmaf(a[g + 2], W3[(size_t)(g + 2) * DIM_OUT + j], s2);
            s3 = fmaf(a[g + 3], W3[(size_t)(g + 3) * DIM_OUT + j], s3);
        }
        W23T[(size_t)j * DIM_HID + h] = (s0 + s1) + (s2 + s3);
    } else if (idx < DIM_OUT * DIM_HID + DIM_OUT) {
        int j = idx - DIM_OUT * DIM_HID;
        float s = 0.f;
        for (int g = 0; g < DIM_HID; ++g) s = fmaf(b2[g], W3[(size_t)g * DIM_OUT + j], s);
        bp2[j] = s;
    }
}

// ---------------- fuse2: WfT[48][520] bf16 = (W1@W23)^T padded  +  bp1 = b1@W23 ----------------
__global__ __launch_bounds__(256) void fuse2(const float* __restrict__ W1,
                                             const float* __restrict__ W23T,
                                             const float* __restrict__ b1,
                                             unsigned short* __restrict__ WfT,
                                             float* __restrict__ bp1) {
    int idx = blockIdx.x * blockDim.x + threadIdx.x;
    if (idx < WROWS * WK) {
        int j = idx / WK, k = idx - j * WK;
        float s = 0.f;
        if (j < DIM_OUT && k < DIM_IN) {
            const float4* a = reinterpret_cast<const float4*>(W1 + (size_t)k * DIM_HID);
            const float4* b = reinterpret_cast<const float4*>(W23T + (size_t)j * DIM_HID);
            float s0 = 0.f, s1 = 0.f, s2 = 0.f, s3 = 0.f;
#pragma unroll 4
            for (int q = 0; q < DIM_HID / 4; ++q) {
                float4 av = a[q], bv = b[q];
                s0 = fmaf(av.x, bv.x, s0);
                s1 = fmaf(av.y, bv.y, s1);
                s2 = fmaf(av.z, bv.z, s2);
                s3 = fmaf(av.w, bv.w, s3);
            }
            s = (s0 + s1) + (s2 + s3);
        }
        WfT[idx] = bf1(s);
    } else if (idx < WROWS * WK + DIM_OUT) {
        int j = idx - WROWS * WK;
        const float* b = W23T + (size_t)j * DIM_HID;
        float s = 0.f;
        for (int h = 0; h < DIM_HID; ++h) s = fmaf(b1[h], b[h], s);
        bp1[j] = s;
    }
}

// ---------------- degree histogram (in-degree over col) ----------------
__global__ void degree_k(const int* __restrict__ col, unsigned* __restrict__ deg, int E) {
    int e = blockIdx.x * blockDim.x + threadIdx.x;
    if (e < E) atomicAdd(&deg[col[e]], 1u);
}

// ---------------- single-block exclusive scan (4 elems/thread) + dinv ----------------
__global__ __launch_bounds__(1024) void scan_block4(const unsigned* __restrict__ deg,
                                                    unsigned* __restrict__ off,
                                                    unsigned* __restrict__ cur,
                                                    float* __restrict__ dinv, int N) {
    const int t = threadIdx.x, lane = t & 63, wid = t >> 6;
    const int N4 = (N + 3) >> 2;
    __shared__ unsigned wsum[16];
    __shared__ unsigned carry_s;
    if (t == 0) carry_s = 0;
    __syncthreads();
    for (int base = 0; base < N4; base += 1024) {
        int i = base + t;
        unsigned d0 = 0, d1 = 0, d2 = 0, d3 = 0;
        if (4 * i + 3 < N) {
            uint4 d = reinterpret_cast<const uint4*>(deg)[i];
            d0 = d.x; d1 = d.y; d2 = d.z; d3 = d.w;
        } else if (4 * i < N) {
            d0 = deg[4 * i];
            if (4 * i + 1 < N) d1 = deg[4 * i + 1];
            if (4 * i + 2 < N) d2 = deg[4 * i + 2];
        }
        unsigned tsum = d0 + d1 + d2 + d3;
        unsigned v = tsum;
#pragma unroll
        for (int o = 1; o < 64; o <<= 1) {
            unsigned u = __shfl_up(v, o);
            if (lane >= o) v += u;
        }
        if (lane == 63) wsum[wid] = v;
        __syncthreads();
        if (wid == 0) {
            unsigned w = (lane < 16) ? wsum[lane] : 0u;
#pragma unroll
            for (int o = 1; o < 16; o <<= 1) {
                unsigned u = __shfl_up(w, o);
                if (lane >= o) w += u;
            }
            if (lane < 16) wsum[lane] = w;
        }
        __syncthreads();
        unsigned excl = carry_s + (wid ? wsum[wid - 1] : 0u) + (v - tsum);
        unsigned o0 = excl, o1 = o0 + d0, o2 = o1 + d1, o3 = o2 + d2;
        if (4 * i + 3 < N) {
            reinterpret_cast<uint4*>(off)[i] = make_uint4(o0, o1, o2, o3);
            reinterpret_cast<uint4*>(cur)[i] = make_uint4(o0, o1, o2, o3);
            reinterpret_cast<float4*>(dinv)[i] =
                make_float4(rsqrtf((float)d0 + 1.f), rsqrtf((float)d1 + 1.f),
                            rsqrtf((float)d2 + 1.f), rsqrtf((float)d3 + 1.f));
        } else if (4 * i < N) {
            off[4 * i] = o0; cur[4 * i] = o0; dinv[4 * i] = rsqrtf((float)d0 + 1.f);
            if (4 * i + 1 < N) { off[4 * i + 1] = o1; cur[4 * i + 1] = o1; dinv[4 * i + 1] = rsqrtf((float)d1 + 1.f); }
            if (4 * i + 2 < N) { off[4 * i + 2] = o2; cur[4 * i + 2] = o2; dinv[4 * i + 2] = rsqrtf((float)d2 + 1.f); }
        }
        __syncthreads();
        if (t == 0) carry_s += wsum[15];
        __syncthreads();
    }
    if (t == 0) off[N] = carry_s;
}

// ---------------- scatter edges into CSR (by col); stores source rows ----------------
__global__ void scatter_k(const int* __restrict__ row, const int* __restrict__ col,
                          unsigned* __restrict__ cur, int* __restrict__ srow, int E) {
    int e = blockIdx.x * blockDim.x + threadIdx.x;
    if (e < E) {
        unsigned p = atomicAdd(&cur[col[e]], 1u);
        srow[p] = row[e];
    }
}

// ---------------- MFMA GEMM: Gb[r][0..40) = bf16( dinv[r] * (X @ Wf)[r][:] ), row stride 64 ----------------
// wave = one 16-row tile; B-frags straight from global WfT (48 KB, L1/L2-hot); no LDS.
__global__ __launch_bounds__(256) void gemm_mfma(const float* __restrict__ X,
                                                 const unsigned short* __restrict__ WfT,
                                                 const float* __restrict__ dinv,
                                                 unsigned short* __restrict__ Gb,
                                                 int N, int ntiles) {
    const int tid  = threadIdx.x;
    const int tile = blockIdx.x * 4 + (tid >> 6);
    if (tile >= ntiles) return;
    const int lane = tid & 63;
    const int r0w  = tile * 16;
    const int rloc = lane & 15;
    const int kgrp = lane >> 4;                     // 0..3
    const int rowA = min(r0w + rloc, N - 1);
    const float* xrow = X + (size_t)rowA * DIM_IN;
    const uint4* Wq = reinterpret_cast<const uint4*>(WfT);

    f32x4 acc0 = {0.f, 0.f, 0.f, 0.f};
    f32x4 acc1 = {0.f, 0.f, 0.f, 0.f};
    f32x4 acc2 = {0.f, 0.f, 0.f, 0.f};

#pragma unroll 4
    for (int k0 = 0; k0 < 512; k0 += 32) {
        const int kb = k0 + kgrp * 8;
        const int c1 = min(kb, 496);                // clamp: cols beyond K=500 hit zero B rows
        const int c2 = min(kb + 4, 496);
        float4 xa = *reinterpret_cast<const float4*>(xrow + c1);
        float4 xb = *reinterpret_cast<const float4*>(xrow + c2);
        short8_t afrag = pack8(xa, xb);

        const int kq = kb >> 3;
        U4S8 b0, b1, b2;
        b0.u = Wq[(0  + rloc) * WKQ + kq];
        b1.u = Wq[(16 + rloc) * WKQ + kq];
        b2.u = Wq[(32 + rloc) * WKQ + kq];

        acc0 = __builtin_amdgcn_mfma_f32_16x16x32_bf16(afrag, b0.s, acc0, 0, 0, 0);
        acc1 = __builtin_amdgcn_mfma_f32_16x16x32_bf16(afrag, b1.s, acc1, 0, 0, 0);
        acc2 = __builtin_amdgcn_mfma_f32_16x16x32_bf16(afrag, b2.s, acc2, 0, 0, 0);
    }

    // C layout: col = lane&15, row = (lane>>4)*4 + i  [m89-verified, r8-passed]
#pragma unroll
    for (int i = 0; i < 4; ++i) {
        const int rg = r0w + kgrp * 4 + i;
        if (rg >= N) continue;
        const float d = dinv[rg];
        unsigned short* gr = Gb + (size_t)rg * GSTR;
        gr[rloc]      = bf1(acc0[i] * d);
        gr[16 + rloc] = bf1(acc1[i] * d);
        if (rloc < 8) gr[32 + rloc] = bf1(acc2[i] * d);
    }
}

// ---------------- aggregation: 16 lanes/node over 128-B padded rows ----------------
// lanes v<10 carry 4 dims each (uint2); one edge gather = exactly one cache line.
// FINAL=0: outb = bf16( d*(d*acc + bias) )   FINAL=1: out = log_softmax(d*acc + b3)
template <int FINAL>
__global__ __launch_bounds__(256) void agg16(const unsigned* __restrict__ off,
                                             const int* __restrict__ srow,
                                             const float* __restrict__ dinv,
                                             const uint2* __restrict__ Gb2,
                                             const float* __restrict__ bias,
                                             uint2* __restrict__ outb,
                                             float4* __restrict__ outf, int N) {
    const int idx = blockIdx.x * blockDim.x + threadIdx.x;
    const int c = idx >> 4;
    const int v = idx & 15;
    if (c >= N) return;

    float a0 = 0.f, a1 = 0.f, a2 = 0.f, a3 = 0.f;
    float f0 = 0.f, f1 = 0.f, f2 = 0.f, f3 = 0.f;

    if (v < 10) {
        const unsigned beg = off[c], end = off[c + 1];
        {   // self loop
            uint2 s = Gb2[(size_t)c * GSTR2 + v];
            bf_unpack(s.x, a0, a1);
            bf_unpack(s.y, a2, a3);
        }
        float t0, t1;
        unsigned e = beg;
        unsigned ea = (beg + 3u) & ~3u; if (ea > end) ea = end;
        for (; e < ea; ++e) {
            uint2 g = Gb2[(size_t)(unsigned)srow[e] * GSTR2 + v];
            bf_unpack(g.x, t0, t1); a0 += t0; a1 += t1;
            bf_unpack(g.y, t0, t1); a2 += t0; a3 += t1;
        }
        for (; e + 8 <= end; e += 8) {              // 8 single-line gathers in flight
            uint4 i0 = *reinterpret_cast<const uint4*>(srow + e);
            uint4 i1 = *reinterpret_cast<const uint4*>(srow + e + 4);
            uint2 g0 = Gb2[(size_t)i0.x * GSTR2 + v];
            uint2 g1 = Gb2[(size_t)i0.y * GSTR2 + v];
            uint2 g2 = Gb2[(size_t)i0.z * GSTR2 + v];
            uint2 g3 = Gb2[(size_t)i0.w * GSTR2 + v];
            uint2 g4 = Gb2[(size_t)i1.x * GSTR2 + v];
            uint2 g5 = Gb2[(size_t)i1.y * GSTR2 + v];
            uint2 g6 = Gb2[(size_t)i1.z * GSTR2 + v];
            uint2 g7 = Gb2[(size_t)i1.w * GSTR2 + v];
            bf_unpack(g0.x, t0, t1); a0 += t0; a1 += t1; bf_unpack(g0.y, t0, t1); a2 += t0; a3 += t1;
            bf_unpack(g1.x, t0, t1); f0 += t0; f1 += t1; bf_unpack(g1.y, t0, t1); f2 += t0; f3 += t1;
            bf_unpack(g2.x, t0, t1); a0 += t0; a1 += t1; bf_unpack(g2.y, t0, t1); a2 += t0; a3 += t1;
            bf_unpack(g3.x, t0, t1); f0 += t0; f1 += t1; bf_unpack(g3.y, t0, t1); f2 += t0; f3 += t1;
            bf_unpack(g4.x, t0, t1); a0 += t0; a1 += t1; bf_unpack(g4.y, t0, t1); a2 += t0; a3 += t1;
            bf_unpack(g5.x, t0, t1); f0 += t0; f1 += t1; bf_unpack(g5.y, t0, t1); f2 += t0; f3 += t1;
            bf_unpack(g6.x, t0, t1); a0 += t0; a1 += t1; bf_unpack(g6.y, t0, t1); a2 += t0; a3 += t1;
            bf_unpack(g7.x, t0, t1); f0 += t0; f1 += t1; bf_unpack(g7.y, t0, t1); f2 += t0; f3 += t1;
        }
        if (e + 4 <= end) {
            uint4 i0 = *reinterpret_cast<const uint4*>(srow + e);
            uint2 g0 = Gb2[(size_t)i0.x * GSTR2 + v];
            uint2 g1 = Gb2[(size_t)i0.y * GSTR2 + v];
            uint2 g2 = Gb2[(size_t)i0.z * GSTR2 + v];
            uint2 g3 = Gb2[(size_t)i0.w * GSTR2 + v];
            bf_unpack(g0.x, t0, t1); a0 += t0; a1 += t1; bf_unpack(g0.y, t0, t1); a2 += t0; a3 += t1;
            bf_unpack(g1.x, t0, t1); f0 += t0; f1 += t1; bf_unpack(g1.y, t0, t1); f2 += t0; f3 += t1;
            bf_unpack(g2.x, t0, t1); a0 += t0; a1 += t1; bf_unpack(g2.y, t0, t1); a2 += t0; a3 += t1;
            bf_unpack(g3.x, t0, t1); f0 += t0; f1 += t1; bf_unpack(g3.y, t0, t1); f2 += t0; f3 += t1;
            e += 4;
        }
        for (; e < end; ++e) {
            uint2 g = Gb2[(size_t)(unsigned)srow[e] * GSTR2 + v];
            bf_unpack(g.x, t0, t1); a0 += t0; a1 += t1;
            bf_unpack(g.y, t0, t1); a2 += t0; a3 += t1;
        }
    }

    const float d = dinv[c];
    float h0 = a0 + f0, h1 = a1 + f1, h2 = a2 + f2, h3 = a3 + f3;

    if (!FINAL) {
        if (v < 10) {
            const float4 bp = reinterpret_cast<const float4*>(bias)[v];
            h0 = d * fmaf(d, h0, bp.x);
            h1 = d * fmaf(d, h1, bp.y);
            h2 = d * fmaf(d, h2, bp.z);
            h3 = d * fmaf(d, h3, bp.w);
            outb[(size_t)c * GSTR2 + v] = make_uint2(bf_pair(h0, h1), bf_pair(h2, h3));
        }
    } else {
        float x0 = 0.f, x1 = 0.f, x2 = 0.f, x3 = 0.f, m = -INFINITY;
        if (v < 10) {
            const float4 b34 = reinterpret_cast<const float4*>(bias)[v];
            x0 = d * h0 + b34.x;
            x1 = d * h1 + b34.y;
            x2 = d * h2 + b34.z;
            x3 = d * h3 + b34.w;
            m = fmaxf(fmaxf(x0, x1), fmaxf(x2, x3));
        }
#pragma unroll
        for (int o = 1; o < 16; o <<= 1) m = fmaxf(m, __shfl_xor(m, o));
        float s = 0.f;
        float e0 = 0.f, e1 = 0.f, e2 = 0.f, e3 = 0.f;
        if (v < 10) {
            e0 = expf(x0 - m); e1 = expf(x1 - m);
            e2 = expf(x2 - m); e3 = expf(x3 - m);
            s = (e0 + e1) + (e2 + e3);
        }
#pragma unroll
        for (int o = 1; o < 16; o <<= 1) s += __shfl_xor(s, o);
        const float lse = m + logf(s);
        if (v < 10)
            outf[(size_t)c * 10 + v] = make_float4(x0 - lse, x1 - lse, x2 - lse, x3 - lse);
    }
}

// ---------------- launch ----------------
extern "C" void kernel_launch(void* const* d_in, const int* in_sizes, int n_in,
                              void* d_out, int out_size, void* d_ws, size_t ws_size,
                              hipStream_t stream) {
    const float* x  = (const float*)d_in[0];
    const int*   ei = (const int*)d_in[1];
    const float* W1 = (const float*)d_in[2];
    const float* b1 = (const float*)d_in[3];
    const float* W2 = (const float*)d_in[4];
    const float* b2 = (const float*)d_in[5];
    const float* W3 = (const float*)d_in[6];
    const float* b3 = (const float*)d_in[7];
    float* out = (float*)d_out;

    const int N = in_sizes[0] / DIM_IN;
    const int E = in_sizes[1] / 2;
    const int* row = ei;       // edge_index[0]
    const int* col = ei + E;   // edge_index[1]

    char* wsp = (char*)d_ws;
    size_t used = 0;
    auto alloc = [&](size_t bytes) -> void* {
        void* p = wsp + used;
        used += (bytes + 255) & ~(size_t)255;
        return p;
    };
    unsigned*       deg   = (unsigned*)alloc((size_t)N * 4);
    unsigned*       off   = (unsigned*)alloc((size_t)(N + 1) * 4);
    unsigned*       cur   = (unsigned*)alloc((size_t)N * 4);
    int*            srow  = (int*)alloc((size_t)E * 4);
    float*          dinv  = (float*)alloc((size_t)N * 4);
    float*          W23T  = (float*)alloc((size_t)DIM_OUT * DIM_HID * 4);
    unsigned short* WfT16 = (unsigned short*)alloc((size_t)WROWS * WK * 2);
    float*          bp1   = (float*)alloc((size_t)DIM_OUT * 4);
    float*          bp2   = (float*)alloc((size_t)DIM_OUT * 4);
    unsigned short* Gb0   = (unsigned short*)alloc((size_t)N * GSTR * 2);
    unsigned short* Gb1   = (unsigned short*)alloc((size_t)N * GSTR * 2);

    // ---- CSR build + normalization ----
    hipMemsetAsync(deg, 0, (size_t)N * 4, stream);
    degree_k<<<(E + 255) / 256, 256, 0, stream>>>(col, deg, E);
    scan_block4<<<1, 1024, 0, stream>>>(deg, off, cur, dinv, N);
    scatter_k<<<(E + 255) / 256, 256, 0, stream>>>(row, col, cur, srow, E);

    // ---- weight fusion: W23T + bp2; WfT (bf16, padded) + bp1 ----
    fuse1<<<(DIM_OUT * DIM_HID + DIM_OUT + 255) / 256, 256, 0, stream>>>(W2, W3, b2, W23T, bp2);
    fuse2<<<(WROWS * WK + DIM_OUT + 255) / 256, 256, 0, stream>>>(W1, W23T, b1, WfT16, bp1);

    // ---- Gb0 = bf16( dinv .* (X @ Wf) ) via MFMA, B direct from global ----
    {
        const int ntiles = (N + 15) / 16;
        gemm_mfma<<<(ntiles + 3) / 4, 256, 0, stream>>>(x, WfT16, dinv, Gb0, N, ntiles);
    }

    // ---- three aggregations (16 lanes/node, 1 line per edge); last fused with softmax ----
    const int aggGrid = (N * 16 + 255) / 256;
    agg16<0><<<aggGrid, 256, 0, stream>>>(off, srow, dinv, (const uint2*)Gb0, bp1, (uint2*)Gb1, nullptr, N);
    agg16<0><<<aggGrid, 256, 0, stream>>>(off, srow, dinv, (const uint2*)Gb1, bp2, (uint2*)Gb0, nullptr, N);
    agg16<1><<<aggGrid, 256, 0, stream>>>(off, srow, dinv, (const uint2*)Gb0, b3, nullptr, (float4*)out, N);
}